// Round 1
// baseline (9805.623 us; speedup 1.0000x reference)
//
#include <hip/hip_runtime.h>
#include <math.h>

#define T_LEN 8192
#define HID   2048
#define NHEAD 16
#define HD    128
#define NBLK  512            // T/M compression blocks
#define SCALE 0.08838834764831845f   // 1/sqrt(128)

// ---------------------------------------------------------------------------
// Generic tiled f32 GEMM: C[M,N] = A[M,K] @ B[K,N], row-major with ld's.
// ---------------------------------------------------------------------------
__global__ __launch_bounds__(256) void sgemm_k(
    const float* __restrict__ A, int lda,
    const float* __restrict__ B, int ldb,
    float* __restrict__ C, int ldc,
    int M, int N, int K)
{
  __shared__ float As[16][65];   // [BK][BM+1]
  __shared__ float Bs[16][65];   // [BK][BN+1]
  const int bm = blockIdx.y * 64;
  const int bn = blockIdx.x * 64;
  const int tid = threadIdx.x;
  const int tx = tid & 15;       // 0..15
  const int ty = tid >> 4;       // 0..15
  float acc[4][4] = {};
  for (int k0 = 0; k0 < K; k0 += 16) {
    #pragma unroll
    for (int i = 0; i < 4; ++i) {
      int f = tid + i * 256;           // 0..1023
      int r = f >> 4, c = f & 15;      // A tile 64x16
      float v = 0.f;
      int gr = bm + r, gc = k0 + c;
      if (gr < M && gc < K) v = A[(size_t)gr * lda + gc];
      As[c][r] = v;
    }
    #pragma unroll
    for (int i = 0; i < 4; ++i) {
      int f = tid + i * 256;
      int r = f >> 6, c = f & 63;      // B tile 16x64
      float v = 0.f;
      int gr = k0 + r, gc = bn + c;
      if (gr < K && gc < N) v = B[(size_t)gr * ldb + gc];
      Bs[r][c] = v;
    }
    __syncthreads();
    #pragma unroll
    for (int kk = 0; kk < 16; ++kk) {
      float a[4], b[4];
      #pragma unroll
      for (int i = 0; i < 4; ++i) a[i] = As[kk][ty * 4 + i];
      #pragma unroll
      for (int j = 0; j < 4; ++j) b[j] = Bs[kk][tx * 4 + j];
      #pragma unroll
      for (int i = 0; i < 4; ++i)
        #pragma unroll
        for (int j = 0; j < 4; ++j) acc[i][j] += a[i] * b[j];
    }
    __syncthreads();
  }
  #pragma unroll
  for (int i = 0; i < 4; ++i) {
    int gr = bm + ty * 4 + i;
    if (gr >= M) continue;
    #pragma unroll
    for (int j = 0; j < 4; ++j) {
      int gc = bn + tx * 4 + j;
      if (gc < N) C[(size_t)gr * ldc + gc] = acc[i][j];
    }
  }
}

// ---------------------------------------------------------------------------
// RoPE cos/sin tables: (T, 32) each.  inv = theta^(-(2i)/64), ang = t*inv.
// ---------------------------------------------------------------------------
__global__ void rope_cs_k(float* __restrict__ ct, float* __restrict__ st)
{
  int idx = blockIdx.x * blockDim.x + threadIdx.x;
  if (idx >= T_LEN * 32) return;
  int t = idx >> 5, i = idx & 31;
  float inv = powf(10000.0f, -(float)(2 * i) / 64.0f);
  float ang = (float)t * inv;
  ct[idx] = cosf(ang);
  st[idx] = sinf(ang);
}

// ---------------------------------------------------------------------------
// q: rope first (dims 0..63 as pairs (d, d+32)), then rmsnorm over 128.
// One wave per (t,h) row, in place.  Layout: row = t*16+h, 128 floats.
// ---------------------------------------------------------------------------
__global__ __launch_bounds__(64) void q_rope_norm_k(
    float* __restrict__ q, const float* __restrict__ ct,
    const float* __restrict__ st, const float* __restrict__ w)
{
  int row = blockIdx.x;            // t*16 + h
  int t = row >> 4;
  int lane = threadIdx.x;          // 0..63
  __shared__ float ls[128];
  float* rp = q + (size_t)row * 128;
  ls[lane] = rp[lane];
  ls[lane + 64] = rp[lane + 64];
  __syncthreads();
  float v0;
  if (lane < 32) {
    float c = ct[t * 32 + lane], s = st[t * 32 + lane];
    v0 = ls[lane] * c - ls[lane + 32] * s;
  } else {
    int i = lane - 32;
    float c = ct[t * 32 + i], s = st[t * 32 + i];
    v0 = ls[i] * s + ls[lane] * c;
  }
  float v1 = ls[lane + 64];
  float ss = v0 * v0 + v1 * v1;
  #pragma unroll
  for (int off = 1; off < 64; off <<= 1) ss += __shfl_xor(ss, off);
  float rn = 1.0f / sqrtf(ss / 128.0f + 1e-6f);
  rp[lane] = v0 * rn * w[lane];
  rp[lane + 64] = v1 * rn * w[lane + 64];
}

// ---------------------------------------------------------------------------
// sw_k: rmsnorm first, THEN rope.  One wave per t row, in place.
// ---------------------------------------------------------------------------
__global__ __launch_bounds__(64) void k_norm_rope_k(
    float* __restrict__ k, const float* __restrict__ ct,
    const float* __restrict__ st, const float* __restrict__ w)
{
  int t = blockIdx.x;
  int lane = threadIdx.x;
  __shared__ float ls[128];
  float* rp = k + (size_t)t * 128;
  float a = rp[lane], b = rp[lane + 64];
  float ss = a * a + b * b;
  #pragma unroll
  for (int off = 1; off < 64; off <<= 1) ss += __shfl_xor(ss, off);
  float rn = 1.0f / sqrtf(ss / 128.0f + 1e-6f);
  a *= rn * w[lane];
  b *= rn * w[lane + 64];
  ls[lane] = a;
  ls[lane + 64] = b;
  __syncthreads();
  float v0;
  if (lane < 32) {
    float c = ct[t * 32 + lane], s = st[t * 32 + lane];
    v0 = ls[lane] * c - ls[lane + 32] * s;
  } else {
    int i = lane - 32;
    float c = ct[t * 32 + i], s = st[t * 32 + i];
    v0 = ls[i] * s + ls[lane] * c;
  }
  rp[lane] = v0;
  rp[lane + 64] = b;
}

// ---------------------------------------------------------------------------
// rmsnorm 128-wide rows in place (for compressed_kv: rmsnorm commutes with
// the gather, so normalize the 512 rows once).
// ---------------------------------------------------------------------------
__global__ __launch_bounds__(64) void rms_rows_k(
    float* __restrict__ x, const float* __restrict__ w)
{
  int r = blockIdx.x;
  int lane = threadIdx.x;
  float* rp = x + (size_t)r * 128;
  float a = rp[lane], b = rp[lane + 64];
  float ss = a * a + b * b;
  #pragma unroll
  for (int off = 1; off < 64; off <<= 1) ss += __shfl_xor(ss, off);
  float rn = 1.0f / sqrtf(ss / 128.0f + 1e-6f);
  rp[lane] = a * rn * w[lane];
  rp[lane + 64] = b * rn * w[lane + 64];
}

// ---------------------------------------------------------------------------
// compress: out[n][d] = sum_m softmax_m(z[n*16+m][d]+bias[m][d]) * c[n*16+m][d]
// One thread per (n, d).
// ---------------------------------------------------------------------------
__global__ void compress_k(
    const float* __restrict__ c, const float* __restrict__ z,
    const float* __restrict__ bias, float* __restrict__ out, int D)
{
  int idx = blockIdx.x * blockDim.x + threadIdx.x;
  if (idx >= NBLK * D) return;
  int n = idx / D, d = idx % D;
  float zb[16];
  float mx = -INFINITY;
  #pragma unroll
  for (int m = 0; m < 16; ++m) {
    float v = z[(size_t)(n * 16 + m) * D + d] + bias[m * D + d];
    zb[m] = v;
    mx = fmaxf(mx, v);
  }
  float s = 0.f;
  #pragma unroll
  for (int m = 0; m < 16; ++m) { zb[m] = expf(zb[m] - mx); s += zb[m]; }
  float acc = 0.f;
  #pragma unroll
  for (int m = 0; m < 16; ++m) acc += zb[m] * c[(size_t)(n * 16 + m) * D + d];
  out[idx] = acc / s;
}

// ---------------------------------------------------------------------------
// Index scores + iterative top-64 per t.  Lowest-index tie-break.
// top_idx[t][j] = block index, or -1 when the pick is -inf (invalid).
// ---------------------------------------------------------------------------
__global__ __launch_bounds__(256) void topk_k(
    const float* __restrict__ qi,    // (T, 4, 64)
    const float* __restrict__ wih,   // (T, 4)
    const float* __restrict__ kcomp, // (512, 64)
    int* __restrict__ top_idx)       // (T, 64)
{
  int t = blockIdx.x;
  int tid = threadIdx.x;
  __shared__ float qs[256];
  __shared__ float wh[4];
  __shared__ float sc[512];
  __shared__ float wmax[4];
  __shared__ int   widx[4];
  qs[tid] = qi[(size_t)t * 256 + tid];
  if (tid < 4) wh[tid] = wih[(size_t)t * 4 + tid];
  __syncthreads();
  for (int n = tid; n < 512; n += 256) {
    float sco;
    if (n * 16 + 15 < t) {
      sco = 0.f;
      #pragma unroll
      for (int hh = 0; hh < 4; ++hh) {
        float d = 0.f;
        for (int cc = 0; cc < 64; ++cc) d += qs[hh * 64 + cc] * kcomp[(size_t)n * 64 + cc];
        sco += wh[hh] * fmaxf(d, 0.f);
      }
    } else {
      sco = -INFINITY;
    }
    sc[n] = sco;
  }
  __syncthreads();
  for (int j = 0; j < 64; ++j) {
    float bv = -INFINITY;
    int bi = 0x7fffffff;
    for (int n = tid; n < 512; n += 256) {
      float v = sc[n];
      if (v > bv || (v == bv && n < bi)) { bv = v; bi = n; }
    }
    #pragma unroll
    for (int off = 32; off >= 1; off >>= 1) {
      float ov = __shfl_xor(bv, off);
      int   oi = __shfl_xor(bi, off);
      if (ov > bv || (ov == bv && oi < bi)) { bv = ov; bi = oi; }
    }
    int wv = tid >> 6;
    if ((tid & 63) == 0) { wmax[wv] = bv; widx[wv] = bi; }
    __syncthreads();
    if (tid == 0) {
      float fv = wmax[0]; int fi = widx[0];
      #pragma unroll
      for (int ww = 1; ww < 4; ++ww)
        if (wmax[ww] > fv || (wmax[ww] == fv && widx[ww] < fi)) { fv = wmax[ww]; fi = widx[ww]; }
      if (fv == -INFINITY) fi = -1;
      top_idx[(size_t)t * 64 + j] = fi;
      if (fi >= 0) sc[fi] = -INFINITY;
    }
    __syncthreads();
  }
}

// ---------------------------------------------------------------------------
// Sparse attention over the 64 selected (pre-normalized) compressed-KV rows.
// One block per t; writes attn (t, h, d) layout.
// ---------------------------------------------------------------------------
__global__ __launch_bounds__(256) void sparse_attn_k(
    const float* __restrict__ q,     // (T, 16, 128)
    const float* __restrict__ nckv,  // (512, 128) rmsnorm'd
    const int* __restrict__ top_idx, // (T, 64)
    float* __restrict__ attn)        // (T, 16, 128)
{
  int t = blockIdx.x;
  int tid = threadIdx.x;
  __shared__ float skv[64][132];
  __shared__ float qs[16][132];
  __shared__ float sc[16][65];
  __shared__ int ivals[64];
  if (tid < 64) ivals[tid] = top_idx[(size_t)t * 64 + tid];
  __syncthreads();
  {
    int r = tid >> 2;
    int c0 = (tid & 3) * 32;
    int gi = ivals[r] >= 0 ? ivals[r] : 0;
    #pragma unroll
    for (int i = 0; i < 32; ++i)
      skv[r][c0 + i] = nckv[(size_t)gi * 128 + c0 + i];
  }
  for (int e = tid; e < 2048; e += 256)
    qs[e >> 7][e & 127] = q[(size_t)t * 2048 + e];
  __syncthreads();
  for (int e = tid; e < 1024; e += 256) {
    int h = e >> 6, k = e & 63;
    const float4* qa = (const float4*)qs[h];
    const float4* kb = (const float4*)skv[k];
    float d = 0.f;
    #pragma unroll
    for (int i = 0; i < 32; ++i) {
      float4 a = qa[i], b = kb[i];
      d += a.x * b.x + a.y * b.y + a.z * b.z + a.w * b.w;
    }
    sc[h][k] = (ivals[k] >= 0) ? d * SCALE : -INFINITY;
  }
  __syncthreads();
  int h = tid >> 4;
  int d0 = (tid & 15) * 8;
  float m = -INFINITY;
  #pragma unroll
  for (int k = 0; k < 64; ++k) m = fmaxf(m, sc[h][k]);
  float o[8] = {};
  if (m > -INFINITY) {
    float l = 0.f;
    for (int k = 0; k < 64; ++k) {
      float p = expf(sc[h][k] - m);
      l += p;
      #pragma unroll
      for (int i = 0; i < 8; ++i) o[i] += p * skv[k][d0 + i];
    }
    float inv = 1.0f / l;
    #pragma unroll
    for (int i = 0; i < 8; ++i) o[i] *= inv;
  }
  #pragma unroll
  for (int i = 0; i < 8; ++i)
    attn[(size_t)t * 2048 + h * 128 + d0 + i] = o[i];
}

// ---------------------------------------------------------------------------
// Sliding-window attention (window = previous 256 positions incl. self),
// flash-style.  One block per (64-query tile, head); attn += result.
// ---------------------------------------------------------------------------
__global__ __launch_bounds__(256) void win_attn_k(
    const float* __restrict__ q,   // (T, 16, 128)
    const float* __restrict__ kw,  // (T, 128)
    const float* __restrict__ vw,  // (T, 128)
    float* __restrict__ attn)      // (T, 16, 128) +=
{
  int qt = blockIdx.x;      // 0..127
  int h  = blockIdx.y;      // 0..15
  int tid = threadIdx.x;
  __shared__ float qs[64][132];
  __shared__ float ks[64][132];
  __shared__ float vs[64][132];
  __shared__ float ss[64][65];
  for (int e = tid; e < 8192; e += 256) {
    int r = e >> 7, c = e & 127;
    qs[r][c] = q[(size_t)(qt * 64 + r) * 2048 + h * 128 + c];
  }
  int qr = tid & 63;
  int d0 = (tid >> 6) * 32;
  float4 acc4[8] = {};
  float m = -INFINITY, l = 0.f;
  int kt0 = qt >= 4 ? qt - 4 : 0;
  for (int kt = kt0; kt <= qt; ++kt) {
    __syncthreads();
    for (int e = tid; e < 8192; e += 256) {
      int r = e >> 7, c = e & 127;
      ks[r][c] = kw[(size_t)(kt * 64 + r) * 128 + c];
      vs[r][c] = vw[(size_t)(kt * 64 + r) * 128 + c];
    }
    __syncthreads();
    for (int e = tid; e < 4096; e += 256) {
      int r = e >> 6, k = e & 63;
      const float4* qa = (const float4*)qs[r];
      const float4* kb = (const float4*)ks[k];
      float d = 0.f;
      #pragma unroll
      for (int i = 0; i < 32; ++i) {
        float4 a = qa[i], b = kb[i];
        d += a.x * b.x + a.y * b.y + a.z * b.z + a.w * b.w;
      }
      int qg = qt * 64 + r, kg = kt * 64 + k;
      bool ok = (kg <= qg) && (kg > qg - 256);
      ss[r][k] = ok ? d * SCALE : -INFINITY;
    }
    __syncthreads();
    float rm = -INFINITY;
    #pragma unroll
    for (int k = 0; k < 64; ++k) rm = fmaxf(rm, ss[qr][k]);
    float nm = fmaxf(m, rm);
    if (nm > -INFINITY) {
      float f = expf(m - nm);   // m == -inf -> 0
      l *= f;
      #pragma unroll
      for (int i = 0; i < 8; ++i) {
        acc4[i].x *= f; acc4[i].y *= f; acc4[i].z *= f; acc4[i].w *= f;
      }
      const int v0 = d0 >> 2;
      for (int k = 0; k < 64; ++k) {
        float p = expf(ss[qr][k] - nm);
        l += p;
        const float4* vk = (const float4*)vs[k];
        #pragma unroll
        for (int i = 0; i < 8; ++i) {
          float4 v = vk[v0 + i];
          acc4[i].x += p * v.x; acc4[i].y += p * v.y;
          acc4[i].z += p * v.z; acc4[i].w += p * v.w;
        }
      }
      m = nm;
    }
  }
  float inv = 1.0f / l;
  size_t base = (size_t)(qt * 64 + qr) * 2048 + h * 128 + d0;
  #pragma unroll
  for (int i = 0; i < 8; ++i) {
    attn[base + i * 4 + 0] += acc4[i].x * inv;
    attn[base + i * 4 + 1] += acc4[i].y * inv;
    attn[base + i * 4 + 2] += acc4[i].z * inv;
    attn[base + i * 4 + 3] += acc4[i].w * inv;
  }
}

// ---------------------------------------------------------------------------
extern "C" void kernel_launch(void* const* d_in, const int* in_sizes, int n_in,
                              void* d_out, int out_size, void* d_ws, size_t ws_size,
                              hipStream_t stream)
{
  const float* h        = (const float*)d_in[0];
  const float* w_qc     = (const float*)d_in[1];
  const float* w_qup    = (const float*)d_in[2];
  const float* kvc_w    = (const float*)d_in[3];
  const float* kvc_wz   = (const float*)d_in[4];
  const float* kvc_bias = (const float*)d_in[5];
  const float* k_proj_w = (const float*)d_in[6];
  const float* v_proj_w = (const float*)d_in[7];
  const float* idx_c_w  = (const float*)d_in[8];
  const float* idx_c_wz = (const float*)d_in[9];
  const float* idx_c_bias = (const float*)d_in[10];
  const float* w_dq     = (const float*)d_in[11];
  const float* w_iuq    = (const float*)d_in[12];
  const float* w_w      = (const float*)d_in[13];
  const float* q_norm_w = (const float*)d_in[14];
  const float* k_norm_w = (const float*)d_in[15];
  const float* group_w  = (const float*)d_in[16];
  const float* final_w  = (const float*)d_in[17];
  float* out = (float*)d_out;

  float* ws = (float*)d_ws;
  size_t off = 0;
  auto alloc = [&](size_t n) { float* p = ws + off; off += n; return p; };
  float* cosT  = alloc((size_t)T_LEN * 32);
  float* sinT  = alloc((size_t)T_LEN * 32);
  float* qb    = alloc((size_t)T_LEN * 2048);   // q_raw -> q ; later og
  float* attn  = alloc((size_t)T_LEN * 2048);
  float* hq1   = alloc((size_t)T_LEN * 512);
  float* swk   = alloc((size_t)T_LEN * 128);
  float* swv   = alloc((size_t)T_LEN * 128);
  float* cbuf  = alloc((size_t)T_LEN * 128);
  float* zbuf  = alloc((size_t)T_LEN * 128);
  float* kcomp = alloc((size_t)NBLK * 64);
  float* ckv   = alloc((size_t)NBLK * 128);
  float* dqb   = alloc((size_t)T_LEN * 64);
  float* qib   = alloc((size_t)T_LEN * 256);
  float* wihb  = alloc((size_t)T_LEN * 4);
  int*   topi  = (int*)alloc((size_t)T_LEN * 64);

  // rope tables
  rope_cs_k<<<(T_LEN * 32 + 255) / 256, 256, 0, stream>>>(cosT, sinT);

  // q chain
  sgemm_k<<<dim3(512 / 64, T_LEN / 64), 256, 0, stream>>>(h, HID, w_qc, 512, hq1, 512, T_LEN, 512, HID);
  sgemm_k<<<dim3(2048 / 64, T_LEN / 64), 256, 0, stream>>>(hq1, 512, w_qup, 2048, qb, 2048, T_LEN, 2048, 512);
  q_rope_norm_k<<<T_LEN * 16, 64, 0, stream>>>(qb, cosT, sinT, q_norm_w);

  // sliding-window k/v
  sgemm_k<<<dim3(2, T_LEN / 64), 256, 0, stream>>>(h, HID, k_proj_w, 128, swk, 128, T_LEN, 128, HID);
  k_norm_rope_k<<<T_LEN, 64, 0, stream>>>(swk, cosT, sinT, k_norm_w);
  sgemm_k<<<dim3(2, T_LEN / 64), 256, 0, stream>>>(h, HID, v_proj_w, 128, swv, 128, T_LEN, 128, HID);

  // index compression -> k_comp (512 x 64)
  sgemm_k<<<dim3(1, T_LEN / 64), 256, 0, stream>>>(h, HID, idx_c_w, 64, cbuf, 64, T_LEN, 64, HID);
  sgemm_k<<<dim3(1, T_LEN / 64), 256, 0, stream>>>(h, HID, idx_c_wz, 64, zbuf, 64, T_LEN, 64, HID);
  compress_k<<<(NBLK * 64 + 255) / 256, 256, 0, stream>>>(cbuf, zbuf, idx_c_bias, kcomp, 64);

  // kv compression -> ckv (512 x 128), then rmsnorm rows once
  sgemm_k<<<dim3(2, T_LEN / 64), 256, 0, stream>>>(h, HID, kvc_w, 128, cbuf, 128, T_LEN, 128, HID);
  sgemm_k<<<dim3(2, T_LEN / 64), 256, 0, stream>>>(h, HID, kvc_wz, 128, zbuf, 128, T_LEN, 128, HID);
  compress_k<<<(NBLK * 128 + 255) / 256, 256, 0, stream>>>(cbuf, zbuf, kvc_bias, ckv, 128);
  rms_rows_k<<<NBLK, 64, 0, stream>>>(ckv, k_norm_w);

  // index queries + weights
  sgemm_k<<<dim3(1, T_LEN / 64), 256, 0, stream>>>(h, HID, w_dq, 64, dqb, 64, T_LEN, 64, HID);
  sgemm_k<<<dim3(4, T_LEN / 64), 256, 0, stream>>>(dqb, 64, w_iuq, 256, qib, 256, T_LEN, 256, 64);
  sgemm_k<<<dim3(1, T_LEN / 64), 256, 0, stream>>>(h, HID, w_w, 4, wihb, 4, T_LEN, 4, HID);

  // top-64 selection
  topk_k<<<T_LEN, 256, 0, stream>>>(qib, wihb, kcomp, topi);

  // sparse attention (writes attn), then window attention (attn +=)
  sparse_attn_k<<<T_LEN, 256, 0, stream>>>(qb, ckv, topi, attn);
  win_attn_k<<<dim3(T_LEN / 64, 16), 256, 0, stream>>>(qb, swk, swv, attn);

  // grouped projection: og (aliases qb; q is dead) then final projection
  float* og = qb;
  for (int g = 0; g < 4; ++g)
    sgemm_k<<<dim3(512 / 64, T_LEN / 64), 256, 0, stream>>>(
        attn + g * 512, 2048, group_w + (size_t)g * 512 * 512, 512,
        og + g * 512, 2048, T_LEN, 512, 512);
  sgemm_k<<<dim3(2048 / 64, T_LEN / 64), 256, 0, stream>>>(og, 2048, final_w, 2048, out, 2048, T_LEN, 2048, HID);
}

// Round 2
// 7434.251 us; speedup vs baseline: 1.3190x; 1.3190x over previous
//
#include <hip/hip_runtime.h>
#include <math.h>

#define T_LEN 8192
#define HID   2048
#define NHEAD 16
#define HD    128
#define NBLK  512            // T/M compression blocks
#define SCALE 0.08838834764831845f   // 1/sqrt(128)

// ---------------------------------------------------------------------------
// Generic tiled f32 GEMM: C[M,N] = A[M,K] @ B[K,N], row-major with ld's.
// ---------------------------------------------------------------------------
__global__ __launch_bounds__(256) void sgemm_k(
    const float* __restrict__ A, int lda,
    const float* __restrict__ B, int ldb,
    float* __restrict__ C, int ldc,
    int M, int N, int K)
{
  __shared__ float As[16][65];   // [BK][BM+1]
  __shared__ float Bs[16][65];   // [BK][BN+1]
  const int bm = blockIdx.y * 64;
  const int bn = blockIdx.x * 64;
  const int tid = threadIdx.x;
  const int tx = tid & 15;       // 0..15
  const int ty = tid >> 4;       // 0..15
  float acc[4][4] = {};
  for (int k0 = 0; k0 < K; k0 += 16) {
    #pragma unroll
    for (int i = 0; i < 4; ++i) {
      int f = tid + i * 256;           // 0..1023
      int r = f >> 4, c = f & 15;      // A tile 64x16
      float v = 0.f;
      int gr = bm + r, gc = k0 + c;
      if (gr < M && gc < K) v = A[(size_t)gr * lda + gc];
      As[c][r] = v;
    }
    #pragma unroll
    for (int i = 0; i < 4; ++i) {
      int f = tid + i * 256;
      int r = f >> 6, c = f & 63;      // B tile 16x64
      float v = 0.f;
      int gr = k0 + r, gc = bn + c;
      if (gr < K && gc < N) v = B[(size_t)gr * ldb + gc];
      Bs[r][c] = v;
    }
    __syncthreads();
    #pragma unroll
    for (int kk = 0; kk < 16; ++kk) {
      float a[4], b[4];
      #pragma unroll
      for (int i = 0; i < 4; ++i) a[i] = As[kk][ty * 4 + i];
      #pragma unroll
      for (int j = 0; j < 4; ++j) b[j] = Bs[kk][tx * 4 + j];
      #pragma unroll
      for (int i = 0; i < 4; ++i)
        #pragma unroll
        for (int j = 0; j < 4; ++j) acc[i][j] += a[i] * b[j];
    }
    __syncthreads();
  }
  #pragma unroll
  for (int i = 0; i < 4; ++i) {
    int gr = bm + ty * 4 + i;
    if (gr >= M) continue;
    #pragma unroll
    for (int j = 0; j < 4; ++j) {
      int gc = bn + tx * 4 + j;
      if (gc < N) C[(size_t)gr * ldc + gc] = acc[i][j];
    }
  }
}

// ---------------------------------------------------------------------------
// RoPE cos/sin tables: (T, 32) each.  inv = theta^(-(2i)/64), ang = t*inv.
// ---------------------------------------------------------------------------
__global__ void rope_cs_k(float* __restrict__ ct, float* __restrict__ st)
{
  int idx = blockIdx.x * blockDim.x + threadIdx.x;
  if (idx >= T_LEN * 32) return;
  int t = idx >> 5, i = idx & 31;
  float inv = powf(10000.0f, -(float)(2 * i) / 64.0f);
  float ang = (float)t * inv;
  ct[idx] = cosf(ang);
  st[idx] = sinf(ang);
}

// ---------------------------------------------------------------------------
// q: rope first (dims 0..63 as pairs (d, d+32)), then rmsnorm over 128.
// One wave per (t,h) row, in place.  Layout: row = t*16+h, 128 floats.
// ---------------------------------------------------------------------------
__global__ __launch_bounds__(64) void q_rope_norm_k(
    float* __restrict__ q, const float* __restrict__ ct,
    const float* __restrict__ st, const float* __restrict__ w)
{
  int row = blockIdx.x;            // t*16 + h
  int t = row >> 4;
  int lane = threadIdx.x;          // 0..63
  __shared__ float ls[128];
  float* rp = q + (size_t)row * 128;
  ls[lane] = rp[lane];
  ls[lane + 64] = rp[lane + 64];
  __syncthreads();
  float v0;
  if (lane < 32) {
    float c = ct[t * 32 + lane], s = st[t * 32 + lane];
    v0 = ls[lane] * c - ls[lane + 32] * s;
  } else {
    int i = lane - 32;
    float c = ct[t * 32 + i], s = st[t * 32 + i];
    v0 = ls[i] * s + ls[lane] * c;
  }
  float v1 = ls[lane + 64];
  float ss = v0 * v0 + v1 * v1;
  #pragma unroll
  for (int off = 1; off < 64; off <<= 1) ss += __shfl_xor(ss, off);
  float rn = 1.0f / sqrtf(ss / 128.0f + 1e-6f);
  rp[lane] = v0 * rn * w[lane];
  rp[lane + 64] = v1 * rn * w[lane + 64];
}

// ---------------------------------------------------------------------------
// sw_k: rmsnorm first, THEN rope.  One wave per t row, in place.
// ---------------------------------------------------------------------------
__global__ __launch_bounds__(64) void k_norm_rope_k(
    float* __restrict__ k, const float* __restrict__ ct,
    const float* __restrict__ st, const float* __restrict__ w)
{
  int t = blockIdx.x;
  int lane = threadIdx.x;
  __shared__ float ls[128];
  float* rp = k + (size_t)t * 128;
  float a = rp[lane], b = rp[lane + 64];
  float ss = a * a + b * b;
  #pragma unroll
  for (int off = 1; off < 64; off <<= 1) ss += __shfl_xor(ss, off);
  float rn = 1.0f / sqrtf(ss / 128.0f + 1e-6f);
  a *= rn * w[lane];
  b *= rn * w[lane + 64];
  ls[lane] = a;
  ls[lane + 64] = b;
  __syncthreads();
  float v0;
  if (lane < 32) {
    float c = ct[t * 32 + lane], s = st[t * 32 + lane];
    v0 = ls[lane] * c - ls[lane + 32] * s;
  } else {
    int i = lane - 32;
    float c = ct[t * 32 + i], s = st[t * 32 + i];
    v0 = ls[i] * s + ls[lane] * c;
  }
  rp[lane] = v0;
  rp[lane + 64] = b;
}

// ---------------------------------------------------------------------------
// rmsnorm 128-wide rows in place (for compressed_kv: rmsnorm commutes with
// the gather, so normalize the 512 rows once).
// ---------------------------------------------------------------------------
__global__ __launch_bounds__(64) void rms_rows_k(
    float* __restrict__ x, const float* __restrict__ w)
{
  int r = blockIdx.x;
  int lane = threadIdx.x;
  float* rp = x + (size_t)r * 128;
  float a = rp[lane], b = rp[lane + 64];
  float ss = a * a + b * b;
  #pragma unroll
  for (int off = 1; off < 64; off <<= 1) ss += __shfl_xor(ss, off);
  float rn = 1.0f / sqrtf(ss / 128.0f + 1e-6f);
  rp[lane] = a * rn * w[lane];
  rp[lane + 64] = b * rn * w[lane + 64];
}

// ---------------------------------------------------------------------------
// compress: out[n*sn + d*sd] = sum_m softmax_m(z[n*16+m][d]+bias[m][d]) * c[..]
// One thread per (n, d).  Strides let the index path write transposed.
// ---------------------------------------------------------------------------
__global__ void compress_k(
    const float* __restrict__ c, const float* __restrict__ z,
    const float* __restrict__ bias, float* __restrict__ out,
    int D, int sn, int sd)
{
  int idx = blockIdx.x * blockDim.x + threadIdx.x;
  if (idx >= NBLK * D) return;
  int n = idx / D, d = idx % D;
  float zb[16];
  float mx = -INFINITY;
  #pragma unroll
  for (int m = 0; m < 16; ++m) {
    float v = z[(size_t)(n * 16 + m) * D + d] + bias[m * D + d];
    zb[m] = v;
    mx = fmaxf(mx, v);
  }
  float s = 0.f;
  #pragma unroll
  for (int m = 0; m < 16; ++m) { zb[m] = expf(zb[m] - mx); s += zb[m]; }
  float acc = 0.f;
  #pragma unroll
  for (int m = 0; m < 16; ++m) acc += zb[m] * c[(size_t)(n * 16 + m) * D + d];
  out[(size_t)n * sn + (size_t)d * sd] = acc / s;
}

// ---------------------------------------------------------------------------
// Index scores + top-64, fully in-register, one WAVE per t (4 waves/block).
// kT is k_comp transposed: (64, 512) so score reads are coalesced.
// Lane owns candidates n = lane*8 + s; lowest-index tie-break everywhere.
// No __syncthreads in the selection loop; butterfly __shfl_xor reductions.
// ---------------------------------------------------------------------------
__global__ __launch_bounds__(256) void topk_k(
    const float* __restrict__ qi,    // (T, 4, 64)
    const float* __restrict__ wih,   // (T, 4)
    const float* __restrict__ kT,    // (64, 512)
    int* __restrict__ top_idx)       // (T, 64)
{
  const int wid = threadIdx.x >> 6;
  const int lane = threadIdx.x & 63;
  const int t = blockIdx.x * 4 + wid;
  __shared__ float qs[4][256];
  for (int i = lane; i < 256; i += 64) qs[wid][i] = qi[(size_t)t * 256 + i];
  float wh[4];
  #pragma unroll
  for (int h = 0; h < 4; ++h) wh[h] = wih[(size_t)t * 4 + h];
  __syncthreads();

  // --- scores: d[h][s] = qi[t,h,:] . k_comp[n=lane*8+s, :]
  float d[4][8] = {};
  for (int cc = 0; cc < 64; ++cc) {
    const float4* kp = (const float4*)(kT + (size_t)cc * 512 + lane * 8);
    float4 k0 = kp[0], k1 = kp[1];
    float kv[8] = {k0.x, k0.y, k0.z, k0.w, k1.x, k1.y, k1.z, k1.w};
    #pragma unroll
    for (int h = 0; h < 4; ++h) {
      float qv = qs[wid][h * 64 + cc];
      #pragma unroll
      for (int s = 0; s < 8; ++s) d[h][s] += qv * kv[s];
    }
  }
  float sc[8];
  #pragma unroll
  for (int s = 0; s < 8; ++s) {
    int n = lane * 8 + s;
    float v = wh[0] * fmaxf(d[0][s], 0.f) + wh[1] * fmaxf(d[1][s], 0.f)
            + wh[2] * fmaxf(d[2][s], 0.f) + wh[3] * fmaxf(d[3][s], 0.f);
    sc[s] = (n * 16 + 15 < t) ? v : -INFINITY;
  }

  // --- lane-local best (strict > gives lowest-slot tie-break)
  float bv = -INFINITY; int bs = 0;
  #pragma unroll
  for (int s = 0; s < 8; ++s) if (sc[s] > bv) { bv = sc[s]; bs = s; }

  int* orow = top_idx + (size_t)t * 64;
  for (int j = 0; j < 64; ++j) {
    float v = bv; int n = lane * 8 + bs;
    #pragma unroll
    for (int off = 32; off >= 1; off >>= 1) {
      float ov = __shfl_xor(v, off);
      int   on = __shfl_xor(n, off);
      if (ov > v || (ov == v && on < n)) { v = ov; n = on; }
    }
    if (lane == 0) orow[j] = (v > -INFINITY) ? n : -1;
    if (v > -INFINITY && (n >> 3) == lane) {
      int rs = n & 7;
      #pragma unroll
      for (int s = 0; s < 8; ++s) sc[s] = (s == rs) ? -INFINITY : sc[s];
      bv = -INFINITY; bs = 0;
      #pragma unroll
      for (int s = 0; s < 8; ++s) if (sc[s] > bv) { bv = sc[s]; bs = s; }
    }
  }
}

// ---------------------------------------------------------------------------
// Sparse attention over the 64 selected (pre-normalized) compressed-KV rows.
// One block per t; writes attn (t, h, d) layout.
// ---------------------------------------------------------------------------
__global__ __launch_bounds__(256) void sparse_attn_k(
    const float* __restrict__ q,     // (T, 16, 128)
    const float* __restrict__ nckv,  // (512, 128) rmsnorm'd
    const int* __restrict__ top_idx, // (T, 64)
    float* __restrict__ attn)        // (T, 16, 128)
{
  int t = blockIdx.x;
  int tid = threadIdx.x;
  __shared__ float skv[64][132];
  __shared__ float qs[16][132];
  __shared__ float sc[16][65];
  __shared__ int ivals[64];
  if (tid < 64) ivals[tid] = top_idx[(size_t)t * 64 + tid];
  __syncthreads();
  {
    int r = tid >> 2;
    int c0 = (tid & 3) * 32;
    int gi = ivals[r] >= 0 ? ivals[r] : 0;
    #pragma unroll
    for (int i = 0; i < 32; ++i)
      skv[r][c0 + i] = nckv[(size_t)gi * 128 + c0 + i];
  }
  for (int e = tid; e < 2048; e += 256)
    qs[e >> 7][e & 127] = q[(size_t)t * 2048 + e];
  __syncthreads();
  for (int e = tid; e < 1024; e += 256) {
    int h = e >> 6, k = e & 63;
    const float4* qa = (const float4*)qs[h];
    const float4* kb = (const float4*)skv[k];
    float d = 0.f;
    #pragma unroll
    for (int i = 0; i < 32; ++i) {
      float4 a = qa[i], b = kb[i];
      d += a.x * b.x + a.y * b.y + a.z * b.z + a.w * b.w;
    }
    sc[h][k] = (ivals[k] >= 0) ? d * SCALE : -INFINITY;
  }
  __syncthreads();
  int h = tid >> 4;
  int d0 = (tid & 15) * 8;
  float m = -INFINITY;
  #pragma unroll
  for (int k = 0; k < 64; ++k) m = fmaxf(m, sc[h][k]);
  float o[8] = {};
  if (m > -INFINITY) {
    float l = 0.f;
    for (int k = 0; k < 64; ++k) {
      float p = expf(sc[h][k] - m);
      l += p;
      #pragma unroll
      for (int i = 0; i < 8; ++i) o[i] += p * skv[k][d0 + i];
    }
    float inv = 1.0f / l;
    #pragma unroll
    for (int i = 0; i < 8; ++i) o[i] *= inv;
  }
  #pragma unroll
  for (int i = 0; i < 8; ++i)
    attn[(size_t)t * 2048 + h * 128 + d0 + i] = o[i];
}

// ---------------------------------------------------------------------------
// Sliding-window attention (window = previous 256 positions incl. self),
// flash-style.  One block per (64-query tile, head); attn += result.
// ---------------------------------------------------------------------------
__global__ __launch_bounds__(256) void win_attn_k(
    const float* __restrict__ q,   // (T, 16, 128)
    const float* __restrict__ kw,  // (T, 128)
    const float* __restrict__ vw,  // (T, 128)
    float* __restrict__ attn)      // (T, 16, 128) +=
{
  int qt = blockIdx.x;      // 0..127
  int h  = blockIdx.y;      // 0..15
  int tid = threadIdx.x;
  __shared__ float qs[64][132];
  __shared__ float ks[64][132];
  __shared__ float vs[64][132];
  __shared__ float ss[64][65];
  for (int e = tid; e < 8192; e += 256) {
    int r = e >> 7, c = e & 127;
    qs[r][c] = q[(size_t)(qt * 64 + r) * 2048 + h * 128 + c];
  }
  int qr = tid & 63;
  int d0 = (tid >> 6) * 32;
  float4 acc4[8] = {};
  float m = -INFINITY, l = 0.f;
  int kt0 = qt >= 4 ? qt - 4 : 0;
  for (int kt = kt0; kt <= qt; ++kt) {
    __syncthreads();
    for (int e = tid; e < 8192; e += 256) {
      int r = e >> 7, c = e & 127;
      ks[r][c] = kw[(size_t)(kt * 64 + r) * 128 + c];
      vs[r][c] = vw[(size_t)(kt * 64 + r) * 128 + c];
    }
    __syncthreads();
    for (int e = tid; e < 4096; e += 256) {
      int r = e >> 6, k = e & 63;
      const float4* qa = (const float4*)qs[r];
      const float4* kb = (const float4*)ks[k];
      float d = 0.f;
      #pragma unroll
      for (int i = 0; i < 32; ++i) {
        float4 a = qa[i], b = kb[i];
        d += a.x * b.x + a.y * b.y + a.z * b.z + a.w * b.w;
      }
      int qg = qt * 64 + r, kg = kt * 64 + k;
      bool ok = (kg <= qg) && (kg > qg - 256);
      ss[r][k] = ok ? d * SCALE : -INFINITY;
    }
    __syncthreads();
    float rm = -INFINITY;
    #pragma unroll
    for (int k = 0; k < 64; ++k) rm = fmaxf(rm, ss[qr][k]);
    float nm = fmaxf(m, rm);
    if (nm > -INFINITY) {
      float f = expf(m - nm);   // m == -inf -> 0
      l *= f;
      #pragma unroll
      for (int i = 0; i < 8; ++i) {
        acc4[i].x *= f; acc4[i].y *= f; acc4[i].z *= f; acc4[i].w *= f;
      }
      const int v0 = d0 >> 2;
      for (int k = 0; k < 64; ++k) {
        float p = expf(ss[qr][k] - nm);
        l += p;
        const float4* vk = (const float4*)vs[k];
        #pragma unroll
        for (int i = 0; i < 8; ++i) {
          float4 v = vk[v0 + i];
          acc4[i].x += p * v.x; acc4[i].y += p * v.y;
          acc4[i].z += p * v.z; acc4[i].w += p * v.w;
        }
      }
      m = nm;
    }
  }
  float inv = 1.0f / l;
  size_t base = (size_t)(qt * 64 + qr) * 2048 + h * 128 + d0;
  #pragma unroll
  for (int i = 0; i < 8; ++i) {
    attn[base + i * 4 + 0] += acc4[i].x * inv;
    attn[base + i * 4 + 1] += acc4[i].y * inv;
    attn[base + i * 4 + 2] += acc4[i].z * inv;
    attn[base + i * 4 + 3] += acc4[i].w * inv;
  }
}

// ---------------------------------------------------------------------------
extern "C" void kernel_launch(void* const* d_in, const int* in_sizes, int n_in,
                              void* d_out, int out_size, void* d_ws, size_t ws_size,
                              hipStream_t stream)
{
  const float* h        = (const float*)d_in[0];
  const float* w_qc     = (const float*)d_in[1];
  const float* w_qup    = (const float*)d_in[2];
  const float* kvc_w    = (const float*)d_in[3];
  const float* kvc_wz   = (const float*)d_in[4];
  const float* kvc_bias = (const float*)d_in[5];
  const float* k_proj_w = (const float*)d_in[6];
  const float* v_proj_w = (const float*)d_in[7];
  const float* idx_c_w  = (const float*)d_in[8];
  const float* idx_c_wz = (const float*)d_in[9];
  const float* idx_c_bias = (const float*)d_in[10];
  const float* w_dq     = (const float*)d_in[11];
  const float* w_iuq    = (const float*)d_in[12];
  const float* w_w      = (const float*)d_in[13];
  const float* q_norm_w = (const float*)d_in[14];
  const float* k_norm_w = (const float*)d_in[15];
  const float* group_w  = (const float*)d_in[16];
  const float* final_w  = (const float*)d_in[17];
  float* out = (float*)d_out;

  float* ws = (float*)d_ws;
  size_t off = 0;
  auto alloc = [&](size_t n) { float* p = ws + off; off += n; return p; };
  float* cosT  = alloc((size_t)T_LEN * 32);
  float* sinT  = alloc((size_t)T_LEN * 32);
  float* qb    = alloc((size_t)T_LEN * 2048);   // q_raw -> q ; later og
  float* attn  = alloc((size_t)T_LEN * 2048);
  float* hq1   = alloc((size_t)T_LEN * 512);
  float* swk   = alloc((size_t)T_LEN * 128);
  float* swv   = alloc((size_t)T_LEN * 128);
  float* cbuf  = alloc((size_t)T_LEN * 128);
  float* zbuf  = alloc((size_t)T_LEN * 128);
  float* kT    = alloc((size_t)64 * NBLK);      // transposed k_comp
  float* ckv   = alloc((size_t)NBLK * 128);
  float* dqb   = alloc((size_t)T_LEN * 64);
  float* qib   = alloc((size_t)T_LEN * 256);
  float* wihb  = alloc((size_t)T_LEN * 4);
  int*   topi  = (int*)alloc((size_t)T_LEN * 64);

  // rope tables
  rope_cs_k<<<(T_LEN * 32 + 255) / 256, 256, 0, stream>>>(cosT, sinT);

  // q chain
  sgemm_k<<<dim3(512 / 64, T_LEN / 64), 256, 0, stream>>>(h, HID, w_qc, 512, hq1, 512, T_LEN, 512, HID);
  sgemm_k<<<dim3(2048 / 64, T_LEN / 64), 256, 0, stream>>>(hq1, 512, w_qup, 2048, qb, 2048, T_LEN, 2048, 512);
  q_rope_norm_k<<<T_LEN * 16, 64, 0, stream>>>(qb, cosT, sinT, q_norm_w);

  // sliding-window k/v
  sgemm_k<<<dim3(2, T_LEN / 64), 256, 0, stream>>>(h, HID, k_proj_w, 128, swk, 128, T_LEN, 128, HID);
  k_norm_rope_k<<<T_LEN, 64, 0, stream>>>(swk, cosT, sinT, k_norm_w);
  sgemm_k<<<dim3(2, T_LEN / 64), 256, 0, stream>>>(h, HID, v_proj_w, 128, swv, 128, T_LEN, 128, HID);

  // index compression -> kT (64 x 512, transposed k_comp)
  sgemm_k<<<dim3(1, T_LEN / 64), 256, 0, stream>>>(h, HID, idx_c_w, 64, cbuf, 64, T_LEN, 64, HID);
  sgemm_k<<<dim3(1, T_LEN / 64), 256, 0, stream>>>(h, HID, idx_c_wz, 64, zbuf, 64, T_LEN, 64, HID);
  compress_k<<<(NBLK * 64 + 255) / 256, 256, 0, stream>>>(cbuf, zbuf, idx_c_bias, kT, 64, 1, NBLK);

  // kv compression -> ckv (512 x 128), then rmsnorm rows once
  sgemm_k<<<dim3(2, T_LEN / 64), 256, 0, stream>>>(h, HID, kvc_w, 128, cbuf, 128, T_LEN, 128, HID);
  sgemm_k<<<dim3(2, T_LEN / 64), 256, 0, stream>>>(h, HID, kvc_wz, 128, zbuf, 128, T_LEN, 128, HID);
  compress_k<<<(NBLK * 128 + 255) / 256, 256, 0, stream>>>(cbuf, zbuf, kvc_bias, ckv, 128, 128, 1);
  rms_rows_k<<<NBLK, 64, 0, stream>>>(ckv, k_norm_w);

  // index queries + weights
  sgemm_k<<<dim3(1, T_LEN / 64), 256, 0, stream>>>(h, HID, w_dq, 64, dqb, 64, T_LEN, 64, HID);
  sgemm_k<<<dim3(4, T_LEN / 64), 256, 0, stream>>>(dqb, 64, w_iuq, 256, qib, 256, T_LEN, 256, 64);
  sgemm_k<<<dim3(1, T_LEN / 64), 256, 0, stream>>>(h, HID, w_w, 4, wihb, 4, T_LEN, 4, HID);

  // top-64 selection (one wave per t, 4 waves per block)
  topk_k<<<T_LEN / 4, 256, 0, stream>>>(qib, wihb, kT, topi);

  // sparse attention (writes attn), then window attention (attn +=)
  sparse_attn_k<<<T_LEN, 256, 0, stream>>>(qb, ckv, topi, attn);
  win_attn_k<<<dim3(T_LEN / 64, 16), 256, 0, stream>>>(qb, swk, swv, attn);

  // grouped projection: og (aliases qb; q is dead) then final projection
  float* og = qb;
  for (int g = 0; g < 4; ++g)
    sgemm_k<<<dim3(512 / 64, T_LEN / 64), 256, 0, stream>>>(
        attn + g * 512, 2048, group_w + (size_t)g * 512 * 512, 512,
        og + g * 512, 2048, T_LEN, 512, 512);
  sgemm_k<<<dim3(2048 / 64, T_LEN / 64), 256, 0, stream>>>(og, 2048, final_w, 2048, out, 2048, T_LEN, 2048, HID);
}

// Round 3
// 2134.255 us; speedup vs baseline: 4.5944x; 3.4833x over previous
//
#include <hip/hip_runtime.h>
#include <math.h>

#define T_LEN 8192
#define HID   2048
#define NHEAD 16
#define HD    128
#define NBLK  512
#define SCALE 0.08838834764831845f   // 1/sqrt(128)

typedef unsigned short u16;
typedef unsigned short u16x8 __attribute__((ext_vector_type(8)));
typedef float f32x4 __attribute__((ext_vector_type(4)));

// ---- bf16 <-> f32 via bit ops (RNE), no dependence on __bf16 conversions ----
__device__ __forceinline__ u16 f2b(float f) {
  unsigned int u = __float_as_uint(f);
  return (u16)((u + 0x7fffu + ((u >> 16) & 1u)) >> 16);
}
__device__ __forceinline__ float b2f(u16 s) {
  return __uint_as_float(((unsigned int)s) << 16);
}

// ---- async global->LDS, 16B per lane (dest must be wave-linear) ----
__device__ __forceinline__ void gload16(const u16* g, u16* l) {
  __builtin_amdgcn_global_load_lds(
      (__attribute__((address_space(1))) void*)(uintptr_t)g,
      (__attribute__((address_space(3))) void*)(unsigned int)(uintptr_t)l,
      16, 0, 0);
}

// ---- MFMA 16x16x32 bf16 via inline asm (D/C tied) ----
__device__ __forceinline__ void mfma16(f32x4& d, u16x8 a, u16x8 b) {
  asm("v_mfma_f32_16x16x32_bf16 %0, %1, %2, %0" : "+v"(d) : "v"(a), "v"(b));
}

// ---------------------------------------------------------------------------
// bf16 MFMA GEMM: C[M,N] = A[M,K] @ Bt[N,K]^T.  M=gridDim.y*128, N=gridDim.x*128,
// K%32==0.  A,Bt row-major bf16.  OUT_BF16 selects C dtype.
// m97 structure: 128x128 tile, BK=32, 4 waves (2x2), 4x4 frags/wave,
// global_load_lds staging, 2 barriers per K-step.
// ---------------------------------------------------------------------------
template<int OUT_BF16>
__global__ __launch_bounds__(256) void bgemm_k(
    const u16* __restrict__ A, int lda,
    const u16* __restrict__ Bt, int ldb,
    void* __restrict__ Cp, int ldc, int K)
{
  __shared__ __align__(16) u16 Al[128 * 32];
  __shared__ __align__(16) u16 Bl[128 * 32];
  const int tid = threadIdx.x;
  const int lane = tid & 63;
  const int bm = blockIdx.y * 128;
  const int bn = blockIdx.x * 128;
  const int wr = ((tid >> 6) >> 1) * 64;   // wave row offset (0/64)
  const int wc = ((tid >> 6) & 1) * 64;    // wave col offset (0/64)
  const int r0 = tid >> 2;                 // staging row (0..63)
  const int c0 = (tid & 3) * 8;            // staging k-offset
  const u16* ga0 = A  + (size_t)(bm + r0) * lda + c0;
  const u16* ga1 = ga0 + (size_t)64 * lda;
  const u16* gb0 = Bt + (size_t)(bn + r0) * ldb + c0;
  const u16* gb1 = gb0 + (size_t)64 * ldb;
  u16* la0 = Al + tid * 8;
  u16* la1 = Al + (tid + 256) * 8;
  u16* lb0 = Bl + tid * 8;
  u16* lb1 = Bl + (tid + 256) * 8;

  f32x4 zero = {0.f, 0.f, 0.f, 0.f};
  f32x4 acc[4][4];
  #pragma unroll
  for (int m = 0; m < 4; ++m)
    #pragma unroll
    for (int n = 0; n < 4; ++n) acc[m][n] = zero;

  const int ar = wr + (lane & 15);
  const int br = wc + (lane & 15);
  const int ko = (lane >> 4) * 8;

  for (int k0 = 0; k0 < K; k0 += 32) {
    gload16(ga0 + k0, la0);
    gload16(ga1 + k0, la1);
    gload16(gb0 + k0, lb0);
    gload16(gb1 + k0, lb1);
    __syncthreads();                 // compiler emits vmcnt(0) before barrier
    u16x8 af[4], bfr[4];
    #pragma unroll
    for (int m = 0; m < 4; ++m)
      af[m] = *(const u16x8*)(Al + (size_t)(ar + m * 16) * 32 + ko);
    #pragma unroll
    for (int n = 0; n < 4; ++n)
      bfr[n] = *(const u16x8*)(Bl + (size_t)(br + n * 16) * 32 + ko);
    #pragma unroll
    for (int m = 0; m < 4; ++m)
      #pragma unroll
      for (int n = 0; n < 4; ++n) mfma16(acc[m][n], af[m], bfr[n]);
    __syncthreads();                 // protect LDS before next stage
  }
  asm volatile("s_nop 7\n\ts_nop 7"); // MFMA->VALU read hazard guard
  const int er = (lane >> 4) * 4;
  const int ec = lane & 15;
  #pragma unroll
  for (int m = 0; m < 4; ++m)
    #pragma unroll
    for (int n = 0; n < 4; ++n)
      #pragma unroll
      for (int r = 0; r < 4; ++r) {
        size_t idx = (size_t)(bm + wr + m * 16 + er + r) * ldc + (bn + wc + n * 16 + ec);
        if (OUT_BF16) ((u16*)Cp)[idx] = f2b(acc[m][n][r]);
        else          ((float*)Cp)[idx] = acc[m][n][r];
      }
}

// ---------------------------------------------------------------------------
// Generic tiled f32 GEMM (kept for the index/top-k path — selection stability).
// ---------------------------------------------------------------------------
__global__ __launch_bounds__(256) void sgemm_k(
    const float* __restrict__ A, int lda,
    const float* __restrict__ B, int ldb,
    float* __restrict__ C, int ldc,
    int M, int N, int K)
{
  __shared__ float As[16][65];
  __shared__ float Bs[16][65];
  const int bm = blockIdx.y * 64;
  const int bn = blockIdx.x * 64;
  const int tid = threadIdx.x;
  const int tx = tid & 15;
  const int ty = tid >> 4;
  float acc[4][4] = {};
  for (int k0 = 0; k0 < K; k0 += 16) {
    #pragma unroll
    for (int i = 0; i < 4; ++i) {
      int f = tid + i * 256;
      int r = f >> 4, c = f & 15;
      float v = 0.f;
      int gr = bm + r, gc = k0 + c;
      if (gr < M && gc < K) v = A[(size_t)gr * lda + gc];
      As[c][r] = v;
    }
    #pragma unroll
    for (int i = 0; i < 4; ++i) {
      int f = tid + i * 256;
      int r = f >> 6, c = f & 63;
      float v = 0.f;
      int gr = k0 + r, gc = bn + c;
      if (gr < K && gc < N) v = B[(size_t)gr * ldb + gc];
      Bs[r][c] = v;
    }
    __syncthreads();
    #pragma unroll
    for (int kk = 0; kk < 16; ++kk) {
      float a[4], b[4];
      #pragma unroll
      for (int i = 0; i < 4; ++i) a[i] = As[kk][ty * 4 + i];
      #pragma unroll
      for (int j = 0; j < 4; ++j) b[j] = Bs[kk][tx * 4 + j];
      #pragma unroll
      for (int i = 0; i < 4; ++i)
        #pragma unroll
        for (int j = 0; j < 4; ++j) acc[i][j] += a[i] * b[j];
    }
    __syncthreads();
  }
  #pragma unroll
  for (int i = 0; i < 4; ++i) {
    int gr = bm + ty * 4 + i;
    if (gr >= M) continue;
    #pragma unroll
    for (int j = 0; j < 4; ++j) {
      int gc = bn + tx * 4 + j;
      if (gc < N) C[(size_t)gr * ldc + gc] = acc[i][j];
    }
  }
}

// ---------------------------------------------------------------------------
// f32 -> bf16 cast (4 elems/thread)
// ---------------------------------------------------------------------------
__global__ void castk(const float* __restrict__ in, u16* __restrict__ out, int n4)
{
  int i = blockIdx.x * 256 + threadIdx.x;
  if (i >= n4) return;
  float4 v = ((const float4*)in)[i];
  unsigned int lo = (unsigned int)f2b(v.x) | ((unsigned int)f2b(v.y) << 16);
  unsigned int hi = (unsigned int)f2b(v.z) | ((unsigned int)f2b(v.w) << 16);
  ((uint2*)out)[i] = make_uint2(lo, hi);
}

// ---------------------------------------------------------------------------
// transpose + cast: in f32 [R][C] -> out bf16 [C][R]
// ---------------------------------------------------------------------------
__global__ __launch_bounds__(256) void tcast_k(
    const float* __restrict__ in, u16* __restrict__ outT, int R, int C)
{
  __shared__ float t[32][33];
  int bc = blockIdx.x * 32, br = blockIdx.y * 32;
  int lx = threadIdx.x & 31, ly = threadIdx.x >> 5;
  #pragma unroll
  for (int i = 0; i < 32; i += 8) {
    int r = br + ly + i, c = bc + lx;
    t[ly + i][lx] = (r < R && c < C) ? in[(size_t)r * C + c] : 0.f;
  }
  __syncthreads();
  #pragma unroll
  for (int i = 0; i < 32; i += 8) {
    int c = bc + ly + i, r = br + lx;
    if (c < C && r < R) outT[(size_t)c * R + r] = f2b(t[lx][ly + i]);
  }
}

// ---------------------------------------------------------------------------
// Concat the 4 index-path weights into Bcat f32 (2048 x 228)
// ---------------------------------------------------------------------------
__global__ void concat_idx_k(const float* __restrict__ a, const float* __restrict__ b,
                             const float* __restrict__ c, const float* __restrict__ d,
                             float* __restrict__ o)
{
  int i = blockIdx.x * 256 + threadIdx.x;
  if (i >= 2048 * 228) return;
  int r = i / 228, col = i % 228;
  float v = (col < 64)  ? a[r * 64 + col]
          : (col < 128) ? b[r * 64 + col - 64]
          : (col < 192) ? c[r * 64 + col - 128]
          :               d[r * 4 + col - 192];
  o[i] = v;
}

// ---------------------------------------------------------------------------
// RoPE cos/sin tables: (T, 32) each.
// ---------------------------------------------------------------------------
__global__ void rope_cs_k(float* __restrict__ ct, float* __restrict__ st)
{
  int idx = blockIdx.x * blockDim.x + threadIdx.x;
  if (idx >= T_LEN * 32) return;
  int t = idx >> 5, i = idx & 31;
  float inv = powf(10000.0f, -(float)(2 * i) / 64.0f);
  float ang = (float)t * inv;
  ct[idx] = cosf(ang);
  st[idx] = sinf(ang);
}

// ---------------------------------------------------------------------------
// q (bf16, row = t*16+h): rope then rmsnorm, in place.
// ---------------------------------------------------------------------------
__global__ __launch_bounds__(64) void q_rope_norm_k(
    u16* __restrict__ q, const float* __restrict__ ct,
    const float* __restrict__ st, const float* __restrict__ w)
{
  int row = blockIdx.x;
  int t = row >> 4;
  int lane = threadIdx.x;
  __shared__ float ls[128];
  u16* rp = q + (size_t)row * 128;
  ls[lane] = b2f(rp[lane]);
  ls[lane + 64] = b2f(rp[lane + 64]);
  __syncthreads();
  float v0;
  if (lane < 32) {
    float c = ct[t * 32 + lane], s = st[t * 32 + lane];
    v0 = ls[lane] * c - ls[lane + 32] * s;
  } else {
    int i = lane - 32;
    float c = ct[t * 32 + i], s = st[t * 32 + i];
    v0 = ls[i] * s + ls[lane] * c;
  }
  float v1 = ls[lane + 64];
  float ss = v0 * v0 + v1 * v1;
  #pragma unroll
  for (int off = 1; off < 64; off <<= 1) ss += __shfl_xor(ss, off);
  float rn = 1.0f / sqrtf(ss / 128.0f + 1e-6f);
  rp[lane] = f2b(v0 * rn * w[lane]);
  rp[lane + 64] = f2b(v1 * rn * w[lane + 64]);
}

// ---------------------------------------------------------------------------
// sw_k inside kvout (f32, row stride 512, cols 0..127): rmsnorm then rope.
// ---------------------------------------------------------------------------
__global__ __launch_bounds__(64) void k_norm_rope_k(
    float* __restrict__ kv, const float* __restrict__ ct,
    const float* __restrict__ st, const float* __restrict__ w)
{
  int t = blockIdx.x;
  int lane = threadIdx.x;
  __shared__ float ls[128];
  float* rp = kv + (size_t)t * 512;
  float a = rp[lane], b = rp[lane + 64];
  float ss = a * a + b * b;
  #pragma unroll
  for (int off = 1; off < 64; off <<= 1) ss += __shfl_xor(ss, off);
  float rn = 1.0f / sqrtf(ss / 128.0f + 1e-6f);
  a *= rn * w[lane];
  b *= rn * w[lane + 64];
  ls[lane] = a;
  ls[lane + 64] = b;
  __syncthreads();
  float v0;
  if (lane < 32) {
    float c = ct[t * 32 + lane], s = st[t * 32 + lane];
    v0 = ls[lane] * c - ls[lane + 32] * s;
  } else {
    int i = lane - 32;
    float c = ct[t * 32 + i], s = st[t * 32 + i];
    v0 = ls[i] * s + ls[lane] * c;
  }
  rp[lane] = v0;
  rp[lane + 64] = b;
}

// ---------------------------------------------------------------------------
// rmsnorm 128-wide f32 rows in place (compressed_kv rows).
// ---------------------------------------------------------------------------
__global__ __launch_bounds__(64) void rms_rows_k(
    float* __restrict__ x, const float* __restrict__ w)
{
  int r = blockIdx.x;
  int lane = threadIdx.x;
  float* rp = x + (size_t)r * 128;
  float a = rp[lane], b = rp[lane + 64];
  float ss = a * a + b * b;
  #pragma unroll
  for (int off = 1; off < 64; off <<= 1) ss += __shfl_xor(ss, off);
  float rn = 1.0f / sqrtf(ss / 128.0f + 1e-6f);
  rp[lane] = a * rn * w[lane];
  rp[lane + 64] = b * rn * w[lane + 64];
}

// ---------------------------------------------------------------------------
// compress with input row-stride ldin: out[n*sn + d*sd]
// ---------------------------------------------------------------------------
__global__ void compress_k(
    const float* __restrict__ c, const float* __restrict__ z, int ldin,
    const float* __restrict__ bias, float* __restrict__ out,
    int D, int sn, int sd)
{
  int idx = blockIdx.x * blockDim.x + threadIdx.x;
  if (idx >= NBLK * D) return;
  int n = idx / D, d = idx % D;
  float zb[16];
  float mx = -INFINITY;
  #pragma unroll
  for (int m = 0; m < 16; ++m) {
    float v = z[(size_t)(n * 16 + m) * ldin + d] + bias[m * D + d];
    zb[m] = v;
    mx = fmaxf(mx, v);
  }
  float s = 0.f;
  #pragma unroll
  for (int m = 0; m < 16; ++m) { zb[m] = expf(zb[m] - mx); s += zb[m]; }
  float acc = 0.f;
  #pragma unroll
  for (int m = 0; m < 16; ++m) acc += zb[m] * c[(size_t)(n * 16 + m) * ldin + d];
  out[(size_t)n * sn + (size_t)d * sd] = acc / s;
}

// ---------------------------------------------------------------------------
// Top-64 per t, fully in-register, one wave per t (4 waves/block).
// ---------------------------------------------------------------------------
__global__ __launch_bounds__(256) void topk_k(
    const float* __restrict__ qi,    // (T, 4, 64)
    const float* __restrict__ wih, int wst,
    const float* __restrict__ kT,    // (64, 512)
    int* __restrict__ top_idx)       // (T, 64)
{
  const int wid = threadIdx.x >> 6;
  const int lane = threadIdx.x & 63;
  const int t = blockIdx.x * 4 + wid;
  __shared__ float qs[4][256];
  for (int i = lane; i < 256; i += 64) qs[wid][i] = qi[(size_t)t * 256 + i];
  float wh[4];
  #pragma unroll
  for (int h = 0; h < 4; ++h) wh[h] = wih[(size_t)t * wst + h];
  __syncthreads();

  float d[4][8] = {};
  for (int cc = 0; cc < 64; ++cc) {
    const float4* kp = (const float4*)(kT + (size_t)cc * 512 + lane * 8);
    float4 k0 = kp[0], k1 = kp[1];
    float kv[8] = {k0.x, k0.y, k0.z, k0.w, k1.x, k1.y, k1.z, k1.w};
    #pragma unroll
    for (int h = 0; h < 4; ++h) {
      float qv = qs[wid][h * 64 + cc];
      #pragma unroll
      for (int s = 0; s < 8; ++s) d[h][s] += qv * kv[s];
    }
  }
  float sc[8];
  #pragma unroll
  for (int s = 0; s < 8; ++s) {
    int n = lane * 8 + s;
    float v = wh[0] * fmaxf(d[0][s], 0.f) + wh[1] * fmaxf(d[1][s], 0.f)
            + wh[2] * fmaxf(d[2][s], 0.f) + wh[3] * fmaxf(d[3][s], 0.f);
    sc[s] = (n * 16 + 15 < t) ? v : -INFINITY;
  }
  float bv = -INFINITY; int bs = 0;
  #pragma unroll
  for (int s = 0; s < 8; ++s) if (sc[s] > bv) { bv = sc[s]; bs = s; }

  int* orow = top_idx + (size_t)t * 64;
  for (int j = 0; j < 64; ++j) {
    float v = bv; int n = lane * 8 + bs;
    #pragma unroll
    for (int off = 32; off >= 1; off >>= 1) {
      float ov = __shfl_xor(v, off);
      int   on = __shfl_xor(n, off);
      if (ov > v || (ov == v && on < n)) { v = ov; n = on; }
    }
    if (lane == 0) orow[j] = (v > -INFINITY) ? n : -1;
    if (v > -INFINITY && (n >> 3) == lane) {
      int rs = n & 7;
      #pragma unroll
      for (int s = 0; s < 8; ++s) sc[s] = (s == rs) ? -INFINITY : sc[s];
      bv = -INFINITY; bs = 0;
      #pragma unroll
      for (int s = 0; s < 8; ++s) if (sc[s] > bv) { bv = sc[s]; bs = s; }
    }
  }
}

// ---------------------------------------------------------------------------
// Sparse attention (q bf16, ckv f32 pre-normalized) -> attn bf16 (writes).
// ---------------------------------------------------------------------------
__global__ __launch_bounds__(256) void sparse_attn_k(
    const u16* __restrict__ q,       // (T, 16, 128) bf16
    const float* __restrict__ nckv,  // (512, 128)
    const int* __restrict__ top_idx, // (T, 64)
    u16* __restrict__ attn)          // (T, 16, 128) bf16
{
  int t = blockIdx.x;
  int tid = threadIdx.x;
  __shared__ float skv[64][132];
  __shared__ float qs[16][132];
  __shared__ float sc[16][65];
  __shared__ int ivals[64];
  if (tid < 64) ivals[tid] = top_idx[(size_t)t * 64 + tid];
  __syncthreads();
  {
    int r = tid >> 2;
    int c0 = (tid & 3) * 32;
    int gi = ivals[r] >= 0 ? ivals[r] : 0;
    #pragma unroll
    for (int i = 0; i < 32; ++i)
      skv[r][c0 + i] = nckv[(size_t)gi * 128 + c0 + i];
  }
  for (int e = tid; e < 2048; e += 256)
    qs[e >> 7][e & 127] = b2f(q[(size_t)t * 2048 + e]);
  __syncthreads();
  for (int e = tid; e < 1024; e += 256) {
    int h = e >> 6, k = e & 63;
    const float4* qa = (const float4*)qs[h];
    const float4* kb = (const float4*)skv[k];
    float d = 0.f;
    #pragma unroll
    for (int i = 0; i < 32; ++i) {
      float4 a = qa[i], b = kb[i];
      d += a.x * b.x + a.y * b.y + a.z * b.z + a.w * b.w;
    }
    sc[h][k] = (ivals[k] >= 0) ? d * SCALE : -INFINITY;
  }
  __syncthreads();
  int h = tid >> 4;
  int d0 = (tid & 15) * 8;
  float m = -INFINITY;
  #pragma unroll
  for (int k = 0; k < 64; ++k) m = fmaxf(m, sc[h][k]);
  float o[8] = {};
  if (m > -INFINITY) {
    float l = 0.f;
    for (int k = 0; k < 64; ++k) {
      float p = expf(sc[h][k] - m);
      l += p;
      #pragma unroll
      for (int i = 0; i < 8; ++i) o[i] += p * skv[k][d0 + i];
    }
    float inv = 1.0f / l;
    #pragma unroll
    for (int i = 0; i < 8; ++i) o[i] *= inv;
  }
  #pragma unroll
  for (int i = 0; i < 8; ++i)
    attn[(size_t)t * 2048 + h * 128 + d0 + i] = f2b(o[i]);
}

// ---------------------------------------------------------------------------
// Sliding-window attention; q bf16, fused kv f32 (stride 512: k@0, v@128),
// attn bf16 +=.
// ---------------------------------------------------------------------------
__global__ __launch_bounds__(256) void win_attn_k(
    const u16* __restrict__ q,     // (T, 16, 128) bf16
    const float* __restrict__ kv,  // (T, 512)
    u16* __restrict__ attn)        // (T, 16, 128) bf16 +=
{
  int qt = blockIdx.x;
  int h  = blockIdx.y;
  int tid = threadIdx.x;
  __shared__ float qs[64][132];
  __shared__ float ks[64][132];
  __shared__ float vs[64][132];
  __shared__ float ss[64][65];
  for (int e = tid; e < 8192; e += 256) {
    int r = e >> 7, c = e & 127;
    qs[r][c] = b2f(q[(size_t)(qt * 64 + r) * 2048 + h * 128 + c]);
  }
  int qr = tid & 63;
  int d0 = (tid >> 6) * 32;
  float4 acc4[8] = {};
  float m = -INFINITY, l = 0.f;
  int kt0 = qt >= 4 ? qt - 4 : 0;
  for (int kt = kt0; kt <= qt; ++kt) {
    __syncthreads();
    for (int e = tid; e < 8192; e += 256) {
      int r = e >> 7, c = e & 127;
      ks[r][c] = kv[(size_t)(kt * 64 + r) * 512 + c];
      vs[r][c] = kv[(size_t)(kt * 64 + r) * 512 + 128 + c];
    }
    __syncthreads();
    for (int e = tid; e < 4096; e += 256) {
      int r = e >> 6, k = e & 63;
      const float4* qa = (const float4*)qs[r];
      const float4* kb = (const float4*)ks[k];
      float d = 0.f;
      #pragma unroll
      for (int i = 0; i < 32; ++i) {
        float4 a = qa[i], b = kb[i];
        d += a.x * b.x + a.y * b.y + a.z * b.z + a.w * b.w;
      }
      int qg = qt * 64 + r, kg = kt * 64 + k;
      bool ok = (kg <= qg) && (kg > qg - 256);
      ss[r][k] = ok ? d * SCALE : -INFINITY;
    }
    __syncthreads();
    float rm = -INFINITY;
    #pragma unroll
    for (int k = 0; k < 64; ++k) rm = fmaxf(rm, ss[qr][k]);
    float nm = fmaxf(m, rm);
    if (nm > -INFINITY) {
      float f = expf(m - nm);
      l *= f;
      #pragma unroll
      for (int i = 0; i < 8; ++i) {
        acc4[i].x *= f; acc4[i].y *= f; acc4[i].z *= f; acc4[i].w *= f;
      }
      const int v0 = d0 >> 2;
      for (int k = 0; k < 64; ++k) {
        float p = expf(ss[qr][k] - nm);
        l += p;
        const float4* vk = (const float4*)vs[k];
        #pragma unroll
        for (int i = 0; i < 8; ++i) {
          float4 v = vk[v0 + i];
          acc4[i].x += p * v.x; acc4[i].y += p * v.y;
          acc4[i].z += p * v.z; acc4[i].w += p * v.w;
        }
      }
      m = nm;
    }
  }
  float inv = 1.0f / l;
  size_t base = (size_t)(qt * 64 + qr) * 2048 + h * 128 + d0;
  float ov[32] = {
    acc4[0].x, acc4[0].y, acc4[0].z, acc4[0].w,
    acc4[1].x, acc4[1].y, acc4[1].z, acc4[1].w,
    acc4[2].x, acc4[2].y, acc4[2].z, acc4[2].w,
    acc4[3].x, acc4[3].y, acc4[3].z, acc4[3].w,
    acc4[4].x, acc4[4].y, acc4[4].z, acc4[4].w,
    acc4[5].x, acc4[5].y, acc4[5].z, acc4[5].w,
    acc4[6].x, acc4[6].y, acc4[6].z, acc4[6].w,
    acc4[7].x, acc4[7].y, acc4[7].z, acc4[7].w};
  #pragma unroll
  for (int i = 0; i < 32; ++i)
    attn[base + i] = f2b(b2f(attn[base + i]) + ov[i] * inv);
}

// ---------------------------------------------------------------------------
extern "C" void kernel_launch(void* const* d_in, const int* in_sizes, int n_in,
                              void* d_out, int out_size, void* d_ws, size_t ws_size,
                              hipStream_t stream)
{
  const float* h        = (const float*)d_in[0];
  const float* w_qc     = (const float*)d_in[1];
  const float* w_qup    = (const float*)d_in[2];
  const float* kvc_w    = (const float*)d_in[3];
  const float* kvc_wz   = (const float*)d_in[4];
  const float* kvc_bias = (const float*)d_in[5];
  const float* k_proj_w = (const float*)d_in[6];
  const float* v_proj_w = (const float*)d_in[7];
  const float* idx_c_w  = (const float*)d_in[8];
  const float* idx_c_wz = (const float*)d_in[9];
  const float* idx_c_bias = (const float*)d_in[10];
  const float* w_dq     = (const float*)d_in[11];
  const float* w_iuq    = (const float*)d_in[12];
  const float* w_w      = (const float*)d_in[13];
  const float* q_norm_w = (const float*)d_in[14];
  const float* k_norm_w = (const float*)d_in[15];
  const float* group_w  = (const float*)d_in[16];
  const float* final_w  = (const float*)d_in[17];
  float* out = (float*)d_out;

  float* ws = (float*)d_ws;
  size_t off = 0;
  auto alloc = [&](size_t nfloats) { float* p = ws + off; off += nfloats; return p; };
  float* cosT  = alloc((size_t)T_LEN * 32);
  float* sinT  = alloc((size_t)T_LEN * 32);
  u16* qb      = (u16*)alloc((size_t)T_LEN * 1024);   // q bf16; og aliases later
  u16* attnb   = (u16*)alloc((size_t)T_LEN * 1024);   // attn bf16; early sub-alias below
  u16* hb      = (u16*)alloc((size_t)T_LEN * 1024);   // h bf16
  float* kvout = alloc((size_t)T_LEN * 512);          // fused k|v|kvc_c|kvc_z
  float* ibuf  = alloc((size_t)T_LEN * 228);          // idx_c|idx_z|dq|wih
  float* kT    = alloc((size_t)64 * NBLK);
  float* ckv   = alloc((size_t)NBLK * 128);
  float* qib   = alloc((size_t)T_LEN * 256);
  int*   topi  = (int*)alloc((size_t)T_LEN * 64);
  u16* w_qcT   = (u16*)alloc((size_t)512 * 1024);     // 512x2048 bf16
  u16* w_qupT  = (u16*)alloc((size_t)2048 * 256);     // 2048x512 bf16
  u16* kvT     = (u16*)alloc((size_t)512 * 1024);     // 512x2048 bf16 (4 stacked)
  u16* gwT     = (u16*)alloc((size_t)4 * 512 * 256);  // 4x 512x512 bf16
  u16* fwT     = (u16*)alloc((size_t)2048 * 1024);    // 2048x2048 bf16
  // early-phase sub-aliases inside the attnb region (dead before attention):
  float* Bcat  = (float*)attnb;                       // 2048x228 f32
  u16* hq1b    = (u16*)((float*)attnb + 524288);      // 8192x512 bf16
  u16* og      = qb;                                  // q dead after win_attn

  // --- tables & casts/transposes ---
  rope_cs_k<<<(T_LEN * 32 + 255) / 256, 256, 0, stream>>>(cosT, sinT);
  castk<<<(T_LEN * 2048 / 4 + 255) / 256, 256, 0, stream>>>(h, hb, T_LEN * 2048 / 4);
  tcast_k<<<dim3(16, 64), 256, 0, stream>>>(w_qc, w_qcT, 2048, 512);
  tcast_k<<<dim3(64, 16), 256, 0, stream>>>(w_qup, w_qupT, 512, 2048);
  tcast_k<<<dim3(4, 64), 256, 0, stream>>>(k_proj_w, kvT + (size_t)0 * 128 * 2048, 2048, 128);
  tcast_k<<<dim3(4, 64), 256, 0, stream>>>(v_proj_w, kvT + (size_t)1 * 128 * 2048, 2048, 128);
  tcast_k<<<dim3(4, 64), 256, 0, stream>>>(kvc_w,    kvT + (size_t)2 * 128 * 2048, 2048, 128);
  tcast_k<<<dim3(4, 64), 256, 0, stream>>>(kvc_wz,   kvT + (size_t)3 * 128 * 2048, 2048, 128);
  for (int g = 0; g < 4; ++g)
    tcast_k<<<dim3(16, 16), 256, 0, stream>>>(group_w + (size_t)g * 512 * 512,
                                              gwT + (size_t)g * 512 * 512, 512, 512);
  tcast_k<<<dim3(64, 64), 256, 0, stream>>>(final_w, fwT, 2048, 2048);
  concat_idx_k<<<(2048 * 228 + 255) / 256, 256, 0, stream>>>(idx_c_w, idx_c_wz, w_dq, w_w, Bcat);

  // --- q chain (bf16 MFMA) ---
  bgemm_k<1><<<dim3(4, 64), 256, 0, stream>>>(hb, 2048, w_qcT, 2048, hq1b, 512, 2048);
  bgemm_k<1><<<dim3(16, 64), 256, 0, stream>>>(hq1b, 512, w_qupT, 512, qb, 2048, 512);
  q_rope_norm_k<<<T_LEN * 16, 64, 0, stream>>>(qb, cosT, sinT, q_norm_w);

  // --- fused k|v|kvc projections (bf16 MFMA, f32 out) ---
  bgemm_k<0><<<dim3(4, 64), 256, 0, stream>>>(hb, 2048, kvT, 2048, kvout, 512, 2048);
  k_norm_rope_k<<<T_LEN, 64, 0, stream>>>(kvout, cosT, sinT, k_norm_w);
  compress_k<<<(NBLK * 128 + 255) / 256, 256, 0, stream>>>(
      kvout + 256, kvout + 384, 512, kvc_bias, ckv, 128, 128, 1);
  rms_rows_k<<<NBLK, 64, 0, stream>>>(ckv, k_norm_w);

  // --- index path (f32 exact for selection stability) ---
  sgemm_k<<<dim3(4, 128), 256, 0, stream>>>(h, HID, Bcat, 228, ibuf, 228, T_LEN, 228, HID);
  compress_k<<<(NBLK * 64 + 255) / 256, 256, 0, stream>>>(
      ibuf, ibuf + 64, 228, idx_c_bias, kT, 64, 1, NBLK);
  sgemm_k<<<dim3(4, 128), 256, 0, stream>>>(ibuf + 128, 228, w_iuq, 256, qib, 256, T_LEN, 256, 64);
  topk_k<<<T_LEN / 4, 256, 0, stream>>>(qib, ibuf + 192, 228, kT, topi);

  // --- attention ---
  sparse_attn_k<<<T_LEN, 256, 0, stream>>>(qb, ckv, topi, attnb);
  win_attn_k<<<dim3(T_LEN / 64, 16), 256, 0, stream>>>(qb, kvout, attnb);

  // --- output projections (bf16 MFMA) ---
  for (int g = 0; g < 4; ++g)
    bgemm_k<1><<<dim3(4, 64), 256, 0, stream>>>(
        attnb + (size_t)g * 512, 2048, gwT + (size_t)g * 512 * 512, 512,
        og + (size_t)g * 512, 2048, 512);
  bgemm_k<0><<<dim3(16, 64), 256, 0, stream>>>(og, 2048, fwT, 2048, out, 2048, 2048);
}

// Round 4
// 1202.969 us; speedup vs baseline: 8.1512x; 1.7742x over previous
//
#include <hip/hip_runtime.h>
#include <math.h>

#define T_LEN 8192
#define HID   2048
#define NHEAD 16
#define HD    128
#define NBLK  512
#define SCALE 0.08838834764831845f   // 1/sqrt(128)

typedef unsigned short u16;
typedef unsigned short u16x8 __attribute__((ext_vector_type(8)));
typedef float f32x4 __attribute__((ext_vector_type(4)));

// ---- bf16 <-> f32 via bit ops (RNE), no dependence on __bf16 conversions ----
__device__ __forceinline__ u16 f2b(float f) {
  unsigned int u = __float_as_uint(f);
  return (u16)((u + 0x7fffu + ((u >> 16) & 1u)) >> 16);
}
__device__ __forceinline__ float b2f(u16 s) {
  return __uint_as_float(((unsigned int)s) << 16);
}

// ---- async global->LDS, 16B per lane (dest must be wave-linear) ----
__device__ __forceinline__ void gload16(const u16* g, u16* l) {
  __builtin_amdgcn_global_load_lds(
      (__attribute__((address_space(1))) void*)(uintptr_t)g,
      (__attribute__((address_space(3))) void*)(unsigned int)(uintptr_t)l,
      16, 0, 0);
}

// ---- MFMA 16x16x32 bf16 via inline asm (D/C tied) ----
__device__ __forceinline__ void mfma16(f32x4& d, u16x8 a, u16x8 b) {
  asm("v_mfma_f32_16x16x32_bf16 %0, %1, %2, %0" : "+v"(d) : "v"(a), "v"(b));
}

// ---------------------------------------------------------------------------
// bf16 MFMA GEMM: C[M,N] = A[M,K] @ Bt[N,K]^T.  m97 structure, 128x128 tile.
// ---------------------------------------------------------------------------
template<int OUT_BF16>
__global__ __launch_bounds__(256) void bgemm_k(
    const u16* __restrict__ A, int lda,
    const u16* __restrict__ Bt, int ldb,
    void* __restrict__ Cp, int ldc, int K)
{
  __shared__ __align__(16) u16 Al[128 * 32];
  __shared__ __align__(16) u16 Bl[128 * 32];
  const int tid = threadIdx.x;
  const int lane = tid & 63;
  const int bm = blockIdx.y * 128;
  const int bn = blockIdx.x * 128;
  const int wr = ((tid >> 6) >> 1) * 64;
  const int wc = ((tid >> 6) & 1) * 64;
  const int r0 = tid >> 2;
  const int c0 = (tid & 3) * 8;
  const u16* ga0 = A  + (size_t)(bm + r0) * lda + c0;
  const u16* ga1 = ga0 + (size_t)64 * lda;
  const u16* gb0 = Bt + (size_t)(bn + r0) * ldb + c0;
  const u16* gb1 = gb0 + (size_t)64 * ldb;
  u16* la0 = Al + tid * 8;
  u16* la1 = Al + (tid + 256) * 8;
  u16* lb0 = Bl + tid * 8;
  u16* lb1 = Bl + (tid + 256) * 8;

  f32x4 zero = {0.f, 0.f, 0.f, 0.f};
  f32x4 acc[4][4];
  #pragma unroll
  for (int m = 0; m < 4; ++m)
    #pragma unroll
    for (int n = 0; n < 4; ++n) acc[m][n] = zero;

  const int ar = wr + (lane & 15);
  const int br = wc + (lane & 15);
  const int ko = (lane >> 4) * 8;

  for (int k0 = 0; k0 < K; k0 += 32) {
    gload16(ga0 + k0, la0);
    gload16(ga1 + k0, la1);
    gload16(gb0 + k0, lb0);
    gload16(gb1 + k0, lb1);
    __syncthreads();
    u16x8 af[4], bfr[4];
    #pragma unroll
    for (int m = 0; m < 4; ++m)
      af[m] = *(const u16x8*)(Al + (size_t)(ar + m * 16) * 32 + ko);
    #pragma unroll
    for (int n = 0; n < 4; ++n)
      bfr[n] = *(const u16x8*)(Bl + (size_t)(br + n * 16) * 32 + ko);
    #pragma unroll
    for (int m = 0; m < 4; ++m)
      #pragma unroll
      for (int n = 0; n < 4; ++n) mfma16(acc[m][n], af[m], bfr[n]);
    __syncthreads();
  }
  asm volatile("s_nop 7\n\ts_nop 7");
  const int er = (lane >> 4) * 4;
  const int ec = lane & 15;
  #pragma unroll
  for (int m = 0; m < 4; ++m)
    #pragma unroll
    for (int n = 0; n < 4; ++n)
      #pragma unroll
      for (int r = 0; r < 4; ++r) {
        size_t idx = (size_t)(bm + wr + m * 16 + er + r) * ldc + (bn + wc + n * 16 + ec);
        if (OUT_BF16) ((u16*)Cp)[idx] = f2b(acc[m][n][r]);
        else          ((float*)Cp)[idx] = acc[m][n][r];
      }
}

// ---------------------------------------------------------------------------
// Generic tiled f32 GEMM (index/top-k path — selection stability).
// ---------------------------------------------------------------------------
__global__ __launch_bounds__(256) void sgemm_k(
    const float* __restrict__ A, int lda,
    const float* __restrict__ B, int ldb,
    float* __restrict__ C, int ldc,
    int M, int N, int K)
{
  __shared__ float As[16][65];
  __shared__ float Bs[16][65];
  const int bm = blockIdx.y * 64;
  const int bn = blockIdx.x * 64;
  const int tid = threadIdx.x;
  const int tx = tid & 15;
  const int ty = tid >> 4;
  float acc[4][4] = {};
  for (int k0 = 0; k0 < K; k0 += 16) {
    #pragma unroll
    for (int i = 0; i < 4; ++i) {
      int f = tid + i * 256;
      int r = f >> 4, c = f & 15;
      float v = 0.f;
      int gr = bm + r, gc = k0 + c;
      if (gr < M && gc < K) v = A[(size_t)gr * lda + gc];
      As[c][r] = v;
    }
    #pragma unroll
    for (int i = 0; i < 4; ++i) {
      int f = tid + i * 256;
      int r = f >> 6, c = f & 63;
      float v = 0.f;
      int gr = k0 + r, gc = bn + c;
      if (gr < K && gc < N) v = B[(size_t)gr * ldb + gc];
      Bs[r][c] = v;
    }
    __syncthreads();
    #pragma unroll
    for (int kk = 0; kk < 16; ++kk) {
      float a[4], b[4];
      #pragma unroll
      for (int i = 0; i < 4; ++i) a[i] = As[kk][ty * 4 + i];
      #pragma unroll
      for (int j = 0; j < 4; ++j) b[j] = Bs[kk][tx * 4 + j];
      #pragma unroll
      for (int i = 0; i < 4; ++i)
        #pragma unroll
        for (int j = 0; j < 4; ++j) acc[i][j] += a[i] * b[j];
    }
    __syncthreads();
  }
  #pragma unroll
  for (int i = 0; i < 4; ++i) {
    int gr = bm + ty * 4 + i;
    if (gr >= M) continue;
    #pragma unroll
    for (int j = 0; j < 4; ++j) {
      int gc = bn + tx * 4 + j;
      if (gc < N) C[(size_t)gr * ldc + gc] = acc[i][j];
    }
  }
}

// ---------------------------------------------------------------------------
// f32 -> bf16 cast (4 elems/thread)
// ---------------------------------------------------------------------------
__global__ void castk(const float* __restrict__ in, u16* __restrict__ out, int n4)
{
  int i = blockIdx.x * 256 + threadIdx.x;
  if (i >= n4) return;
  float4 v = ((const float4*)in)[i];
  unsigned int lo = (unsigned int)f2b(v.x) | ((unsigned int)f2b(v.y) << 16);
  unsigned int hi = (unsigned int)f2b(v.z) | ((unsigned int)f2b(v.w) << 16);
  ((uint2*)out)[i] = make_uint2(lo, hi);
}

// ---------------------------------------------------------------------------
// transpose + cast: in f32 [R][C] -> out bf16 [C][R]
// ---------------------------------------------------------------------------
__global__ __launch_bounds__(256) void tcast_k(
    const float* __restrict__ in, u16* __restrict__ outT, int R, int C)
{
  __shared__ float t[32][33];
  int bc = blockIdx.x * 32, br = blockIdx.y * 32;
  int lx = threadIdx.x & 31, ly = threadIdx.x >> 5;
  #pragma unroll
  for (int i = 0; i < 32; i += 8) {
    int r = br + ly + i, c = bc + lx;
    t[ly + i][lx] = (r < R && c < C) ? in[(size_t)r * C + c] : 0.f;
  }
  __syncthreads();
  #pragma unroll
  for (int i = 0; i < 32; i += 8) {
    int c = bc + ly + i, r = br + lx;
    if (c < C && r < R) outT[(size_t)c * R + r] = f2b(t[lx][ly + i]);
  }
}

// ---------------------------------------------------------------------------
// Concat the 4 index-path weights into Bcat f32 (2048 x 228)
// ---------------------------------------------------------------------------
__global__ void concat_idx_k(const float* __restrict__ a, const float* __restrict__ b,
                             const float* __restrict__ c, const float* __restrict__ d,
                             float* __restrict__ o)
{
  int i = blockIdx.x * 256 + threadIdx.x;
  if (i >= 2048 * 228) return;
  int r = i / 228, col = i % 228;
  float v = (col < 64)  ? a[r * 64 + col]
          : (col < 128) ? b[r * 64 + col - 64]
          : (col < 192) ? c[r * 64 + col - 128]
          :               d[r * 4 + col - 192];
  o[i] = v;
}

// ---------------------------------------------------------------------------
// RoPE cos/sin tables: (T, 32) each.
// ---------------------------------------------------------------------------
__global__ void rope_cs_k(float* __restrict__ ct, float* __restrict__ st)
{
  int idx = blockIdx.x * blockDim.x + threadIdx.x;
  if (idx >= T_LEN * 32) return;
  int t = idx >> 5, i = idx & 31;
  float inv = powf(10000.0f, -(float)(2 * i) / 64.0f);
  float ang = (float)t * inv;
  ct[idx] = cosf(ang);
  st[idx] = sinf(ang);
}

// ---------------------------------------------------------------------------
// q (bf16, row = t*16+h): rope then rmsnorm, in place.
// ---------------------------------------------------------------------------
__global__ __launch_bounds__(64) void q_rope_norm_k(
    u16* __restrict__ q, const float* __restrict__ ct,
    const float* __restrict__ st, const float* __restrict__ w)
{
  int row = blockIdx.x;
  int t = row >> 4;
  int lane = threadIdx.x;
  __shared__ float ls[128];
  u16* rp = q + (size_t)row * 128;
  ls[lane] = b2f(rp[lane]);
  ls[lane + 64] = b2f(rp[lane + 64]);
  __syncthreads();
  float v0;
  if (lane < 32) {
    float c = ct[t * 32 + lane], s = st[t * 32 + lane];
    v0 = ls[lane] * c - ls[lane + 32] * s;
  } else {
    int i = lane - 32;
    float c = ct[t * 32 + i], s = st[t * 32 + i];
    v0 = ls[i] * s + ls[lane] * c;
  }
  float v1 = ls[lane + 64];
  float ss = v0 * v0 + v1 * v1;
  #pragma unroll
  for (int off = 1; off < 64; off <<= 1) ss += __shfl_xor(ss, off);
  float rn = 1.0f / sqrtf(ss / 128.0f + 1e-6f);
  rp[lane] = f2b(v0 * rn * w[lane]);
  rp[lane + 64] = f2b(v1 * rn * w[lane + 64]);
}

// ---------------------------------------------------------------------------
// sw_k inside kvout (f32, row stride 512, cols 0..127): rmsnorm then rope.
// ---------------------------------------------------------------------------
__global__ __launch_bounds__(64) void k_norm_rope_k(
    float* __restrict__ kv, const float* __restrict__ ct,
    const float* __restrict__ st, const float* __restrict__ w)
{
  int t = blockIdx.x;
  int lane = threadIdx.x;
  __shared__ float ls[128];
  float* rp = kv + (size_t)t * 512;
  float a = rp[lane], b = rp[lane + 64];
  float ss = a * a + b * b;
  #pragma unroll
  for (int off = 1; off < 64; off <<= 1) ss += __shfl_xor(ss, off);
  float rn = 1.0f / sqrtf(ss / 128.0f + 1e-6f);
  a *= rn * w[lane];
  b *= rn * w[lane + 64];
  ls[lane] = a;
  ls[lane + 64] = b;
  __syncthreads();
  float v0;
  if (lane < 32) {
    float c = ct[t * 32 + lane], s = st[t * 32 + lane];
    v0 = ls[lane] * c - ls[lane + 32] * s;
  } else {
    int i = lane - 32;
    float c = ct[t * 32 + i], s = st[t * 32 + i];
    v0 = ls[i] * s + ls[lane] * c;
  }
  rp[lane] = v0;
  rp[lane + 64] = b;
}

// ---------------------------------------------------------------------------
// rmsnorm 128-wide f32 rows in place (compressed_kv rows).
// ---------------------------------------------------------------------------
__global__ __launch_bounds__(64) void rms_rows_k(
    float* __restrict__ x, const float* __restrict__ w)
{
  int r = blockIdx.x;
  int lane = threadIdx.x;
  float* rp = x + (size_t)r * 128;
  float a = rp[lane], b = rp[lane + 64];
  float ss = a * a + b * b;
  #pragma unroll
  for (int off = 1; off < 64; off <<= 1) ss += __shfl_xor(ss, off);
  float rn = 1.0f / sqrtf(ss / 128.0f + 1e-6f);
  rp[lane] = a * rn * w[lane];
  rp[lane + 64] = b * rn * w[lane + 64];
}

// ---------------------------------------------------------------------------
// compress with input row-stride ldin: out[n*sn + d*sd]
// ---------------------------------------------------------------------------
__global__ void compress_k(
    const float* __restrict__ c, const float* __restrict__ z, int ldin,
    const float* __restrict__ bias, float* __restrict__ out,
    int D, int sn, int sd)
{
  int idx = blockIdx.x * blockDim.x + threadIdx.x;
  if (idx >= NBLK * D) return;
  int n = idx / D, d = idx % D;
  float zb[16];
  float mx = -INFINITY;
  #pragma unroll
  for (int m = 0; m < 16; ++m) {
    float v = z[(size_t)(n * 16 + m) * ldin + d] + bias[m * D + d];
    zb[m] = v;
    mx = fmaxf(mx, v);
  }
  float s = 0.f;
  #pragma unroll
  for (int m = 0; m < 16; ++m) { zb[m] = expf(zb[m] - mx); s += zb[m]; }
  float acc = 0.f;
  #pragma unroll
  for (int m = 0; m < 16; ++m) acc += zb[m] * c[(size_t)(n * 16 + m) * ldin + d];
  out[(size_t)n * sn + (size_t)d * sd] = acc / s;
}

// ---------------------------------------------------------------------------
// Top-64 per t, fully in-register, one wave per t (4 waves/block).
// ---------------------------------------------------------------------------
__global__ __launch_bounds__(256) void topk_k(
    const float* __restrict__ qi,    // (T, 4, 64)
    const float* __restrict__ wih, int wst,
    const float* __restrict__ kT,    // (64, 512)
    int* __restrict__ top_idx)       // (T, 64)
{
  const int wid = threadIdx.x >> 6;
  const int lane = threadIdx.x & 63;
  const int t = blockIdx.x * 4 + wid;
  __shared__ float qs[4][256];
  for (int i = lane; i < 256; i += 64) qs[wid][i] = qi[(size_t)t * 256 + i];
  float wh[4];
  #pragma unroll
  for (int h = 0; h < 4; ++h) wh[h] = wih[(size_t)t * wst + h];
  __syncthreads();

  float d[4][8] = {};
  for (int cc = 0; cc < 64; ++cc) {
    const float4* kp = (const float4*)(kT + (size_t)cc * 512 + lane * 8);
    float4 k0 = kp[0], k1 = kp[1];
    float kv[8] = {k0.x, k0.y, k0.z, k0.w, k1.x, k1.y, k1.z, k1.w};
    #pragma unroll
    for (int h = 0; h < 4; ++h) {
      float qv = qs[wid][h * 64 + cc];
      #pragma unroll
      for (int s = 0; s < 8; ++s) d[h][s] += qv * kv[s];
    }
  }
  float sc[8];
  #pragma unroll
  for (int s = 0; s < 8; ++s) {
    int n = lane * 8 + s;
    float v = wh[0] * fmaxf(d[0][s], 0.f) + wh[1] * fmaxf(d[1][s], 0.f)
            + wh[2] * fmaxf(d[2][s], 0.f) + wh[3] * fmaxf(d[3][s], 0.f);
    sc[s] = (n * 16 + 15 < t) ? v : -INFINITY;
  }
  float bv = -INFINITY; int bs = 0;
  #pragma unroll
  for (int s = 0; s < 8; ++s) if (sc[s] > bv) { bv = sc[s]; bs = s; }

  int* orow = top_idx + (size_t)t * 64;
  for (int j = 0; j < 64; ++j) {
    float v = bv; int n = lane * 8 + bs;
    #pragma unroll
    for (int off = 32; off >= 1; off >>= 1) {
      float ov = __shfl_xor(v, off);
      int   on = __shfl_xor(n, off);
      if (ov > v || (ov == v && on < n)) { v = ov; n = on; }
    }
    if (lane == 0) orow[j] = (v > -INFINITY) ? n : -1;
    if (v > -INFINITY && (n >> 3) == lane) {
      int rs = n & 7;
      #pragma unroll
      for (int s = 0; s < 8; ++s) sc[s] = (s == rs) ? -INFINITY : sc[s];
      bv = -INFINITY; bs = 0;
      #pragma unroll
      for (int s = 0; s < 8; ++s) if (sc[s] > bv) { bv = sc[s]; bs = s; }
    }
  }
}

// ---------------------------------------------------------------------------
// Sparse attention (q bf16, ckv f32 pre-normalized) -> attn bf16 (writes).
// ---------------------------------------------------------------------------
__global__ __launch_bounds__(256) void sparse_attn_k(
    const u16* __restrict__ q,       // (T, 16, 128) bf16
    const float* __restrict__ nckv,  // (512, 128)
    const int* __restrict__ top_idx, // (T, 64)
    u16* __restrict__ attn)          // (T, 16, 128) bf16
{
  int t = blockIdx.x;
  int tid = threadIdx.x;
  __shared__ float skv[64][132];
  __shared__ float qs[16][132];
  __shared__ float sc[16][65];
  __shared__ int ivals[64];
  if (tid < 64) ivals[tid] = top_idx[(size_t)t * 64 + tid];
  __syncthreads();
  {
    int r = tid >> 2;
    int c0 = (tid & 3) * 32;
    int gi = ivals[r] >= 0 ? ivals[r] : 0;
    #pragma unroll
    for (int i = 0; i < 32; ++i)
      skv[r][c0 + i] = nckv[(size_t)gi * 128 + c0 + i];
  }
  for (int e = tid; e < 2048; e += 256)
    qs[e >> 7][e & 127] = b2f(q[(size_t)t * 2048 + e]);
  __syncthreads();
  for (int e = tid; e < 1024; e += 256) {
    int h = e >> 6, k = e & 63;
    const float4* qa = (const float4*)qs[h];
    const float4* kb = (const float4*)skv[k];
    float d = 0.f;
    #pragma unroll
    for (int i = 0; i < 32; ++i) {
      float4 a = qa[i], b = kb[i];
      d += a.x * b.x + a.y * b.y + a.z * b.z + a.w * b.w;
    }
    sc[h][k] = (ivals[k] >= 0) ? d * SCALE : -INFINITY;
  }
  __syncthreads();
  int h = tid >> 4;
  int d0 = (tid & 15) * 8;
  float m = -INFINITY;
  #pragma unroll
  for (int k = 0; k < 64; ++k) m = fmaxf(m, sc[h][k]);
  float o[8] = {};
  if (m > -INFINITY) {
    float l = 0.f;
    for (int k = 0; k < 64; ++k) {
      float p = expf(sc[h][k] - m);
      l += p;
      #pragma unroll
      for (int i = 0; i < 8; ++i) o[i] += p * skv[k][d0 + i];
    }
    float inv = 1.0f / l;
    #pragma unroll
    for (int i = 0; i < 8; ++i) o[i] *= inv;
  }
  #pragma unroll
  for (int i = 0; i < 8; ++i)
    attn[(size_t)t * 2048 + h * 128 + d0 + i] = f2b(o[i]);
}

// ---------------------------------------------------------------------------
// Sliding-window attention, bf16 MFMA flash.  Block = (64-q tile, head),
// 4 waves x 16 q-rows.  K swizzled in LDS, V transposed+padded, P via
// per-wave LDS.  attn (bf16) +=.
// ---------------------------------------------------------------------------
__global__ __launch_bounds__(256) void win_attn_mfma_k(
    const u16* __restrict__ q,     // (T, 16, 128) bf16
    const float* __restrict__ kv,  // (T, 512) f32: k@0, v@128
    u16* __restrict__ attn)        // (T, 16, 128) bf16 +=
{
  const int qt = blockIdx.x, hh = blockIdx.y;
  const int tid = threadIdx.x;
  const int wid = tid >> 6, lane = tid & 63;
  const int low = lane & 15, grp = lane >> 4;

  __shared__ __align__(16) u16 Ks[64 * 128];    // XOR-swizzled rows
  __shared__ __align__(16) u16 Vt[128 * 72];    // transposed, +8 pad
  __shared__ __align__(16) u16 Pl[4][16 * 72];  // per-wave P buffer

  // Q fragments (A-operand: row=low, k=grp*8 within each 32-chunk)
  u16x8 qf[4];
  {
    const u16* qp = q + (size_t)(qt * 64 + wid * 16 + low) * 2048 + hh * 128 + grp * 8;
    #pragma unroll
    for (int kk = 0; kk < 4; ++kk) qf[kk] = *(const u16x8*)(qp + kk * 32);
  }
  f32x4 zero = {0.f, 0.f, 0.f, 0.f};
  f32x4 o[8];
  #pragma unroll
  for (int dt = 0; dt < 8; ++dt) o[dt] = zero;
  float mrow[4] = {-1e30f, -1e30f, -1e30f, -1e30f};
  float lrow[4] = {0.f, 0.f, 0.f, 0.f};

  const int kt0 = qt >= 4 ? qt - 4 : 0;
  const int srow = tid >> 2;          // 0..63
  const int scol = (tid & 3) * 32;    // 0/32/64/96
  for (int kt = kt0; kt <= qt; ++kt) {
    __syncthreads();
    // ---- stage K (bf16, XOR swizzle: u16 col ^= (row&7)<<3) ----
    {
      const float* gk = kv + (size_t)(kt * 64 + srow) * 512 + scol;
      u16 tmp[32];
      #pragma unroll
      for (int i = 0; i < 32; i += 4) {
        float4 v = *(const float4*)(gk + i);
        tmp[i] = f2b(v.x); tmp[i+1] = f2b(v.y); tmp[i+2] = f2b(v.z); tmp[i+3] = f2b(v.w);
      }
      #pragma unroll
      for (int j = 0; j < 4; ++j) {
        int c = scol + j * 8;
        *(u16x8*)(Ks + srow * 128 + (c ^ ((srow & 7) << 3))) = *(const u16x8*)(tmp + j * 8);
      }
      // ---- stage V transposed ----
      const float* gv = gk + 128;
      #pragma unroll
      for (int i = 0; i < 32; i += 4) {
        float4 v = *(const float4*)(gv + i);
        Vt[(scol + i + 0) * 72 + srow] = f2b(v.x);
        Vt[(scol + i + 1) * 72 + srow] = f2b(v.y);
        Vt[(scol + i + 2) * 72 + srow] = f2b(v.z);
        Vt[(scol + i + 3) * 72 + srow] = f2b(v.w);
      }
    }
    __syncthreads();
    // ---- S = Q @ K^T (4 col-tiles of 16) ----
    f32x4 s[4];
    #pragma unroll
    for (int n = 0; n < 4; ++n) {
      s[n] = zero;
      int krow = n * 16 + low;
      #pragma unroll
      for (int kk = 0; kk < 4; ++kk) {
        u16x8 kf = *(const u16x8*)(Ks + krow * 128 + ((kk * 32 + grp * 8) ^ ((krow & 7) << 3)));
        mfma16(s[n], qf[kk], kf);
      }
    }
    asm volatile("s_nop 7\n\ts_nop 7");
    // ---- mask + scale (acc: row = grp*4+r, col = n*16+low) ----
    const int qg = qt * 64 + wid * 16 + grp * 4;
    #pragma unroll
    for (int n = 0; n < 4; ++n) {
      int kg = kt * 64 + n * 16 + low;
      #pragma unroll
      for (int r = 0; r < 4; ++r) {
        bool ok = (kg <= qg + r) && (kg > qg + r - 256);
        s[n][r] = ok ? s[n][r] * SCALE : -1e30f;
      }
    }
    // ---- online softmax per row r ----
    float p[4][4];
    #pragma unroll
    for (int r = 0; r < 4; ++r) {
      float rm = fmaxf(fmaxf(s[0][r], s[1][r]), fmaxf(s[2][r], s[3][r]));
      rm = fmaxf(rm, __shfl_xor(rm, 1));
      rm = fmaxf(rm, __shfl_xor(rm, 2));
      rm = fmaxf(rm, __shfl_xor(rm, 4));
      rm = fmaxf(rm, __shfl_xor(rm, 8));
      float nm = fmaxf(mrow[r], rm);
      float f = __expf(mrow[r] - nm);
      mrow[r] = nm;
      float ps = 0.f;
      #pragma unroll
      for (int n = 0; n < 4; ++n) { p[n][r] = __expf(s[n][r] - nm); ps += p[n][r]; }
      ps += __shfl_xor(ps, 1); ps += __shfl_xor(ps, 2);
      ps += __shfl_xor(ps, 4); ps += __shfl_xor(ps, 8);
      lrow[r] = lrow[r] * f + ps;
      #pragma unroll
      for (int dt = 0; dt < 8; ++dt) o[dt][r] *= f;
    }
    // ---- P -> per-wave LDS (A-frag layout re-shuffle) ----
    u16* pw = Pl[wid];
    #pragma unroll
    for (int n = 0; n < 4; ++n)
      #pragma unroll
      for (int r = 0; r < 4; ++r)
        pw[(grp * 4 + r) * 72 + n * 16 + low] = f2b(p[n][r]);
    // ---- O += P @ V ----
    #pragma unroll
    for (int kk2 = 0; kk2 < 2; ++kk2) {
      u16x8 pa = *(const u16x8*)(pw + low * 72 + kk2 * 32 + grp * 8);
      #pragma unroll
      for (int dt = 0; dt < 8; ++dt) {
        u16x8 vf = *(const u16x8*)(Vt + (dt * 16 + low) * 72 + kk2 * 32 + grp * 8);
        mfma16(o[dt], pa, vf);
      }
    }
  }
  asm volatile("s_nop 7\n\ts_nop 7");
  // ---- epilogue: attn += o / l ----
  float linv[4];
  #pragma unroll
  for (int r = 0; r < 4; ++r) linv[r] = 1.0f / lrow[r];
  u16* ap = attn + (size_t)(qt * 64 + wid * 16 + grp * 4) * 2048 + hh * 128 + low;
  #pragma unroll
  for (int r = 0; r < 4; ++r)
    #pragma unroll
    for (int dt = 0; dt < 8; ++dt) {
      size_t idx = (size_t)r * 2048 + dt * 16;
      ap[idx] = f2b(b2f(ap[idx]) + o[dt][r] * linv[r]);
    }
}

// ---------------------------------------------------------------------------
extern "C" void kernel_launch(void* const* d_in, const int* in_sizes, int n_in,
                              void* d_out, int out_size, void* d_ws, size_t ws_size,
                              hipStream_t stream)
{
  const float* h        = (const float*)d_in[0];
  const float* w_qc     = (const float*)d_in[1];
  const float* w_qup    = (const float*)d_in[2];
  const float* kvc_w    = (const float*)d_in[3];
  const float* kvc_wz   = (const float*)d_in[4];
  const float* kvc_bias = (const float*)d_in[5];
  const float* k_proj_w = (const float*)d_in[6];
  const float* v_proj_w = (const float*)d_in[7];
  const float* idx_c_w  = (const float*)d_in[8];
  const float* idx_c_wz = (const float*)d_in[9];
  const float* idx_c_bias = (const float*)d_in[10];
  const float* w_dq     = (const float*)d_in[11];
  const float* w_iuq    = (const float*)d_in[12];
  const float* w_w      = (const float*)d_in[13];
  const float* q_norm_w = (const float*)d_in[14];
  const float* k_norm_w = (const float*)d_in[15];
  const float* group_w  = (const float*)d_in[16];
  const float* final_w  = (const float*)d_in[17];
  float* out = (float*)d_out;

  float* ws = (float*)d_ws;
  size_t off = 0;
  auto alloc = [&](size_t nfloats) { float* p = ws + off; off += nfloats; return p; };
  float* cosT  = alloc((size_t)T_LEN * 32);
  float* sinT  = alloc((size_t)T_LEN * 32);
  u16* qb      = (u16*)alloc((size_t)T_LEN * 1024);
  u16* attnb   = (u16*)alloc((size_t)T_LEN * 1024);
  u16* hb      = (u16*)alloc((size_t)T_LEN * 1024);
  float* kvout = alloc((size_t)T_LEN * 512);
  float* ibuf  = alloc((size_t)T_LEN * 228);
  float* kT    = alloc((size_t)64 * NBLK);
  float* ckv   = alloc((size_t)NBLK * 128);
  float* qib   = alloc((size_t)T_LEN * 256);
  int*   topi  = (int*)alloc((size_t)T_LEN * 64);
  u16* w_qcT   = (u16*)alloc((size_t)512 * 1024);
  u16* w_qupT  = (u16*)alloc((size_t)2048 * 256);
  u16* kvT     = (u16*)alloc((size_t)512 * 1024);
  u16* gwT     = (u16*)alloc((size_t)4 * 512 * 256);
  u16* fwT     = (u16*)alloc((size_t)2048 * 1024);
  float* Bcat  = (float*)attnb;
  u16* hq1b    = (u16*)((float*)attnb + 524288);
  u16* og      = qb;

  rope_cs_k<<<(T_LEN * 32 + 255) / 256, 256, 0, stream>>>(cosT, sinT);
  castk<<<(T_LEN * 2048 / 4 + 255) / 256, 256, 0, stream>>>(h, hb, T_LEN * 2048 / 4);
  tcast_k<<<dim3(16, 64), 256, 0, stream>>>(w_qc, w_qcT, 2048, 512);
  tcast_k<<<dim3(64, 16), 256, 0, stream>>>(w_qup, w_qupT, 512, 2048);
  tcast_k<<<dim3(4, 64), 256, 0, stream>>>(k_proj_w, kvT + (size_t)0 * 128 * 2048, 2048, 128);
  tcast_k<<<dim3(4, 64), 256, 0, stream>>>(v_proj_w, kvT + (size_t)1 * 128 * 2048, 2048, 128);
  tcast_k<<<dim3(4, 64), 256, 0, stream>>>(kvc_w,    kvT + (size_t)2 * 128 * 2048, 2048, 128);
  tcast_k<<<dim3(4, 64), 256, 0, stream>>>(kvc_wz,   kvT + (size_t)3 * 128 * 2048, 2048, 128);
  for (int g = 0; g < 4; ++g)
    tcast_k<<<dim3(16, 16), 256, 0, stream>>>(group_w + (size_t)g * 512 * 512,
                                              gwT + (size_t)g * 512 * 512, 512, 512);
  tcast_k<<<dim3(64, 64), 256, 0, stream>>>(final_w, fwT, 2048, 2048);
  concat_idx_k<<<(2048 * 228 + 255) / 256, 256, 0, stream>>>(idx_c_w, idx_c_wz, w_dq, w_w, Bcat);

  // q chain (bf16 MFMA)
  bgemm_k<1><<<dim3(4, 64), 256, 0, stream>>>(hb, 2048, w_qcT, 2048, hq1b, 512, 2048);
  bgemm_k<1><<<dim3(16, 64), 256, 0, stream>>>(hq1b, 512, w_qupT, 512, qb, 2048, 512);
  q_rope_norm_k<<<T_LEN * 16, 64, 0, stream>>>(qb, cosT, sinT, q_norm_w);

  // fused k|v|kvc projections
  bgemm_k<0><<<dim3(4, 64), 256, 0, stream>>>(hb, 2048, kvT, 2048, kvout, 512, 2048);
  k_norm_rope_k<<<T_LEN, 64, 0, stream>>>(kvout, cosT, sinT, k_norm_w);
  compress_k<<<(NBLK * 128 + 255) / 256, 256, 0, stream>>>(
      kvout + 256, kvout + 384, 512, kvc_bias, ckv, 128, 128, 1);
  rms_rows_k<<<NBLK, 64, 0, stream>>>(ckv, k_norm_w);

  // index path (f32 exact for selection stability)
  sgemm_k<<<dim3(4, 128), 256, 0, stream>>>(h, HID, Bcat, 228, ibuf, 228, T_LEN, 228, HID);
  compress_k<<<(NBLK * 64 + 255) / 256, 256, 0, stream>>>(
      ibuf, ibuf + 64, 228, idx_c_bias, kT, 64, 1, NBLK);
  sgemm_k<<<dim3(4, 128), 256, 0, stream>>>(ibuf + 128, 228, w_iuq, 256, qib, 256, T_LEN, 256, 64);
  topk_k<<<T_LEN / 4, 256, 0, stream>>>(qib, ibuf + 192, 228, kT, topi);

  // attention
  sparse_attn_k<<<T_LEN, 256, 0, stream>>>(qb, ckv, topi, attnb);
  win_attn_mfma_k<<<dim3(T_LEN / 64, 16), 256, 0, stream>>>(qb, kvout, attnb);

  // output projections (bf16 MFMA)
  for (int g = 0; g < 4; ++g)
    bgemm_k<1><<<dim3(4, 64), 256, 0, stream>>>(
        attnb + (size_t)g * 512, 2048, gwT + (size_t)g * 512 * 512, 512,
        og + (size_t)g * 512, 2048, 512);
  bgemm_k<0><<<dim3(16, 64), 256, 0, stream>>>(og, 2048, fwT, 2048, out, 2048, 2048);
}

// Round 5
// 1060.644 us; speedup vs baseline: 9.2450x; 1.1342x over previous
//
#include <hip/hip_runtime.h>
#include <math.h>

#define T_LEN 8192
#define HID   2048
#define NHEAD 16
#define HD    128
#define NBLK  512
#define NIDX  196                    // 64+64+64+4 used index-path columns
#define SCALE 0.08838834764831845f   // 1/sqrt(128)

typedef unsigned short u16;
typedef unsigned short u16x8 __attribute__((ext_vector_type(8)));
typedef float f32x4 __attribute__((ext_vector_type(4)));

// ---- bf16 <-> f32 via bit ops (RNE) ----
__device__ __forceinline__ u16 f2b(float f) {
  unsigned int u = __float_as_uint(f);
  return (u16)((u + 0x7fffu + ((u >> 16) & 1u)) >> 16);
}
__device__ __forceinline__ float b2f(u16 s) {
  return __uint_as_float(((unsigned int)s) << 16);
}

// ---- async global->LDS, 16B per lane (dest must be wave-linear) ----
__device__ __forceinline__ void gload16(const u16* g, u16* l) {
  __builtin_amdgcn_global_load_lds(
      (__attribute__((address_space(1))) void*)(uintptr_t)g,
      (__attribute__((address_space(3))) void*)(unsigned int)(uintptr_t)l,
      16, 0, 0);
}

// ---- MFMA 16x16x32 bf16 via inline asm (D/C tied) ----
__device__ __forceinline__ void mfma16(f32x4& d, u16x8 a, u16x8 b) {
  asm("v_mfma_f32_16x16x32_bf16 %0, %1, %2, %0" : "+v"(d) : "v"(a), "v"(b));
}

// ---------------------------------------------------------------------------
// bf16 MFMA GEMM: C[M,N] = A[M,K] @ Bt[N,K]^T.  m97 structure, 128x128 tile.
// ---------------------------------------------------------------------------
template<int OUT_BF16>
__global__ __launch_bounds__(256) void bgemm_k(
    const u16* __restrict__ A, int lda,
    const u16* __restrict__ Bt, int ldb,
    void* __restrict__ Cp, int ldc, int K)
{
  __shared__ __align__(16) u16 Al[128 * 32];
  __shared__ __align__(16) u16 Bl[128 * 32];
  const int tid = threadIdx.x;
  const int lane = tid & 63;
  const int bm = blockIdx.y * 128;
  const int bn = blockIdx.x * 128;
  const int wr = ((tid >> 6) >> 1) * 64;
  const int wc = ((tid >> 6) & 1) * 64;
  const int r0 = tid >> 2;
  const int c0 = (tid & 3) * 8;
  const u16* ga0 = A  + (size_t)(bm + r0) * lda + c0;
  const u16* ga1 = ga0 + (size_t)64 * lda;
  const u16* gb0 = Bt + (size_t)(bn + r0) * ldb + c0;
  const u16* gb1 = gb0 + (size_t)64 * ldb;
  u16* la0 = Al + tid * 8;
  u16* la1 = Al + (tid + 256) * 8;
  u16* lb0 = Bl + tid * 8;
  u16* lb1 = Bl + (tid + 256) * 8;

  f32x4 zero = {0.f, 0.f, 0.f, 0.f};
  f32x4 acc[4][4];
  #pragma unroll
  for (int m = 0; m < 4; ++m)
    #pragma unroll
    for (int n = 0; n < 4; ++n) acc[m][n] = zero;

  const int ar = wr + (lane & 15);
  const int br = wc + (lane & 15);
  const int ko = (lane >> 4) * 8;

  for (int k0 = 0; k0 < K; k0 += 32) {
    gload16(ga0 + k0, la0);
    gload16(ga1 + k0, la1);
    gload16(gb0 + k0, lb0);
    gload16(gb1 + k0, lb1);
    __syncthreads();
    u16x8 af[4], bfr[4];
    #pragma unroll
    for (int m = 0; m < 4; ++m)
      af[m] = *(const u16x8*)(Al + (size_t)(ar + m * 16) * 32 + ko);
    #pragma unroll
    for (int n = 0; n < 4; ++n)
      bfr[n] = *(const u16x8*)(Bl + (size_t)(br + n * 16) * 32 + ko);
    #pragma unroll
    for (int m = 0; m < 4; ++m)
      #pragma unroll
      for (int n = 0; n < 4; ++n) mfma16(acc[m][n], af[m], bfr[n]);
    __syncthreads();
  }
  asm volatile("s_nop 7\n\ts_nop 7");
  const int er = (lane >> 4) * 4;
  const int ec = lane & 15;
  #pragma unroll
  for (int m = 0; m < 4; ++m)
    #pragma unroll
    for (int n = 0; n < 4; ++n)
      #pragma unroll
      for (int r = 0; r < 4; ++r) {
        size_t idx = (size_t)(bm + wr + m * 16 + er + r) * ldc + (bn + wc + n * 16 + ec);
        if (OUT_BF16) ((u16*)Cp)[idx] = f2b(acc[m][n][r]);
        else          ((float*)Cp)[idx] = acc[m][n][r];
      }
}

// ---------------------------------------------------------------------------
// f32 GEMM with split-K: blockIdx.z selects K-chunk; writes partials
// P[z][M][ldc].  (index/top-k path — selection stability in f32)
// ---------------------------------------------------------------------------
__global__ __launch_bounds__(256) void sgemm_splitk_k(
    const float* __restrict__ A, int lda,
    const float* __restrict__ B, int ldb,
    float* __restrict__ P, int ldc,
    int M, int N, int kchunk)
{
  __shared__ float As[16][65];
  __shared__ float Bs[16][65];
  const int bm = blockIdx.y * 64;
  const int bn = blockIdx.x * 64;
  const int kb = blockIdx.z * kchunk;
  float* C = P + (size_t)blockIdx.z * M * ldc;
  const int tid = threadIdx.x;
  const int tx = tid & 15;
  const int ty = tid >> 4;
  float acc[4][4] = {};
  for (int k0 = 0; k0 < kchunk; k0 += 16) {
    #pragma unroll
    for (int i = 0; i < 4; ++i) {
      int f = tid + i * 256;
      int r = f >> 4, c = f & 15;
      float v = 0.f;
      int gr = bm + r, gc = kb + k0 + c;
      if (gr < M) v = A[(size_t)gr * lda + gc];
      As[c][r] = v;
    }
    #pragma unroll
    for (int i = 0; i < 4; ++i) {
      int f = tid + i * 256;
      int r = f >> 6, c = f & 63;
      float v = 0.f;
      int gr = kb + k0 + r, gc = bn + c;
      if (gc < N) v = B[(size_t)gr * ldb + gc];
      Bs[r][c] = v;
    }
    __syncthreads();
    #pragma unroll
    for (int kk = 0; kk < 16; ++kk) {
      float a[4], b[4];
      #pragma unroll
      for (int i = 0; i < 4; ++i) a[i] = As[kk][ty * 4 + i];
      #pragma unroll
      for (int j = 0; j < 4; ++j) b[j] = Bs[kk][tx * 4 + j];
      #pragma unroll
      for (int i = 0; i < 4; ++i)
        #pragma unroll
        for (int j = 0; j < 4; ++j) acc[i][j] += a[i] * b[j];
    }
    __syncthreads();
  }
  #pragma unroll
  for (int i = 0; i < 4; ++i) {
    int gr = bm + ty * 4 + i;
    if (gr >= M) continue;
    #pragma unroll
    for (int j = 0; j < 4; ++j) {
      int gc = bn + tx * 4 + j;
      if (gc < N) C[(size_t)gr * ldc + gc] = acc[i][j];
    }
  }
}

// ---- sum 4 split-K partials [4][M][ldp] -> out[M][ldo] ----
__global__ void reduce4_k(const float* __restrict__ P, int ldp,
                          float* __restrict__ o, int ldo, int M)
{
  int i = blockIdx.x * 256 + threadIdx.x;
  if (i >= M * ldp) return;
  int r = i / ldp, c = i % ldp;
  size_t st = (size_t)M * ldp;
  float v = P[i] + P[i + st] + P[i + 2 * st] + P[i + 3 * st];
  o[(size_t)r * ldo + c] = v;
}

// ---------------------------------------------------------------------------
// Generic tiled f32 GEMM (small K qib GEMM).
// ---------------------------------------------------------------------------
__global__ __launch_bounds__(256) void sgemm_k(
    const float* __restrict__ A, int lda,
    const float* __restrict__ B, int ldb,
    float* __restrict__ C, int ldc,
    int M, int N, int K)
{
  __shared__ float As[16][65];
  __shared__ float Bs[16][65];
  const int bm = blockIdx.y * 64;
  const int bn = blockIdx.x * 64;
  const int tid = threadIdx.x;
  const int tx = tid & 15;
  const int ty = tid >> 4;
  float acc[4][4] = {};
  for (int k0 = 0; k0 < K; k0 += 16) {
    #pragma unroll
    for (int i = 0; i < 4; ++i) {
      int f = tid + i * 256;
      int r = f >> 4, c = f & 15;
      float v = 0.f;
      int gr = bm + r, gc = k0 + c;
      if (gr < M && gc < K) v = A[(size_t)gr * lda + gc];
      As[c][r] = v;
    }
    #pragma unroll
    for (int i = 0; i < 4; ++i) {
      int f = tid + i * 256;
      int r = f >> 6, c = f & 63;
      float v = 0.f;
      int gr = k0 + r, gc = bn + c;
      if (gr < K && gc < N) v = B[(size_t)gr * ldb + gc];
      Bs[r][c] = v;
    }
    __syncthreads();
    #pragma unroll
    for (int kk = 0; kk < 16; ++kk) {
      float a[4], b[4];
      #pragma unroll
      for (int i = 0; i < 4; ++i) a[i] = As[kk][ty * 4 + i];
      #pragma unroll
      for (int j = 0; j < 4; ++j) b[j] = Bs[kk][tx * 4 + j];
      #pragma unroll
      for (int i = 0; i < 4; ++i)
        #pragma unroll
        for (int j = 0; j < 4; ++j) acc[i][j] += a[i] * b[j];
    }
    __syncthreads();
  }
  #pragma unroll
  for (int i = 0; i < 4; ++i) {
    int gr = bm + ty * 4 + i;
    if (gr >= M) continue;
    #pragma unroll
    for (int j = 0; j < 4; ++j) {
      int gc = bn + tx * 4 + j;
      if (gc < N) C[(size_t)gr * ldc + gc] = acc[i][j];
    }
  }
}

// ---------------------------------------------------------------------------
// f32 -> bf16 cast (4 elems/thread)
// ---------------------------------------------------------------------------
__global__ void castk(const float* __restrict__ in, u16* __restrict__ out, int n4)
{
  int i = blockIdx.x * 256 + threadIdx.x;
  if (i >= n4) return;
  float4 v = ((const float4*)in)[i];
  unsigned int lo = (unsigned int)f2b(v.x) | ((unsigned int)f2b(v.y) << 16);
  unsigned int hi = (unsigned int)f2b(v.z) | ((unsigned int)f2b(v.w) << 16);
  ((uint2*)out)[i] = make_uint2(lo, hi);
}

// ---------------------------------------------------------------------------
// transpose + cast: in f32 [R][C] -> out bf16 [C][R]
// ---------------------------------------------------------------------------
__global__ __launch_bounds__(256) void tcast_k(
    const float* __restrict__ in, u16* __restrict__ outT, int R, int C)
{
  __shared__ float t[32][33];
  int bc = blockIdx.x * 32, br = blockIdx.y * 32;
  int lx = threadIdx.x & 31, ly = threadIdx.x >> 5;
  #pragma unroll
  for (int i = 0; i < 32; i += 8) {
    int r = br + ly + i, c = bc + lx;
    t[ly + i][lx] = (r < R && c < C) ? in[(size_t)r * C + c] : 0.f;
  }
  __syncthreads();
  #pragma unroll
  for (int i = 0; i < 32; i += 8) {
    int c = bc + ly + i, r = br + lx;
    if (c < C && r < R) outT[(size_t)c * R + r] = f2b(t[lx][ly + i]);
  }
}

// ---------------------------------------------------------------------------
// Concat the 4 index-path weights into Bcat f32 (2048 x 196)
// ---------------------------------------------------------------------------
__global__ void concat_idx_k(const float* __restrict__ a, const float* __restrict__ b,
                             const float* __restrict__ c, const float* __restrict__ d,
                             float* __restrict__ o)
{
  int i = blockIdx.x * 256 + threadIdx.x;
  if (i >= 2048 * NIDX) return;
  int r = i / NIDX, col = i % NIDX;
  float v = (col < 64)  ? a[r * 64 + col]
          : (col < 128) ? b[r * 64 + col - 64]
          : (col < 192) ? c[r * 64 + col - 128]
          :               d[r * 4 + col - 192];
  o[i] = v;
}

// ---------------------------------------------------------------------------
// RoPE cos/sin tables: (T, 32) each.
// ---------------------------------------------------------------------------
__global__ void rope_cs_k(float* __restrict__ ct, float* __restrict__ st)
{
  int idx = blockIdx.x * blockDim.x + threadIdx.x;
  if (idx >= T_LEN * 32) return;
  int t = idx >> 5, i = idx & 31;
  float inv = powf(10000.0f, -(float)(2 * i) / 64.0f);
  float ang = (float)t * inv;
  ct[idx] = cosf(ang);
  st[idx] = sinf(ang);
}

// ---------------------------------------------------------------------------
// q (bf16, row = t*16+h): rope then rmsnorm, in place. 4 rows/block (1/wave).
// ---------------------------------------------------------------------------
__global__ __launch_bounds__(256) void q_rope_norm_k(
    u16* __restrict__ q, const float* __restrict__ ct,
    const float* __restrict__ st, const float* __restrict__ w)
{
  int wid = threadIdx.x >> 6;
  int row = blockIdx.x * 4 + wid;
  int t = row >> 4;
  int lane = threadIdx.x & 63;
  __shared__ float ls[4][128];
  u16* rp = q + (size_t)row * 128;
  ls[wid][lane] = b2f(rp[lane]);
  ls[wid][lane + 64] = b2f(rp[lane + 64]);
  __syncthreads();
  float v0;
  if (lane < 32) {
    float c = ct[t * 32 + lane], s = st[t * 32 + lane];
    v0 = ls[wid][lane] * c - ls[wid][lane + 32] * s;
  } else {
    int i = lane - 32;
    float c = ct[t * 32 + i], s = st[t * 32 + i];
    v0 = ls[wid][i] * s + ls[wid][lane] * c;
  }
  float v1 = ls[wid][lane + 64];
  float ss = v0 * v0 + v1 * v1;
  #pragma unroll
  for (int off = 1; off < 64; off <<= 1) ss += __shfl_xor(ss, off);
  float rn = 1.0f / sqrtf(ss / 128.0f + 1e-6f);
  rp[lane] = f2b(v0 * rn * w[lane]);
  rp[lane + 64] = f2b(v1 * rn * w[lane + 64]);
}

// ---------------------------------------------------------------------------
// sw_k inside kvout (f32, row stride 512, cols 0..127): rmsnorm then rope.
// 4 rows per block, one per wave.
// ---------------------------------------------------------------------------
__global__ __launch_bounds__(256) void k_norm_rope_k(
    float* __restrict__ kv, const float* __restrict__ ct,
    const float* __restrict__ st, const float* __restrict__ w)
{
  int wid = threadIdx.x >> 6;
  int t = blockIdx.x * 4 + wid;
  int lane = threadIdx.x & 63;
  __shared__ float ls[4][128];
  float* rp = kv + (size_t)t * 512;
  float a = rp[lane], b = rp[lane + 64];
  float ss = a * a + b * b;
  #pragma unroll
  for (int off = 1; off < 64; off <<= 1) ss += __shfl_xor(ss, off);
  float rn = 1.0f / sqrtf(ss / 128.0f + 1e-6f);
  a *= rn * w[lane];
  b *= rn * w[lane + 64];
  ls[wid][lane] = a;
  ls[wid][lane + 64] = b;
  __syncthreads();
  float v0;
  if (lane < 32) {
    float c = ct[t * 32 + lane], s = st[t * 32 + lane];
    v0 = ls[wid][lane] * c - ls[wid][lane + 32] * s;
  } else {
    int i = lane - 32;
    float c = ct[t * 32 + i], s = st[t * 32 + i];
    v0 = ls[wid][i] * s + ls[wid][lane] * c;
  }
  rp[lane] = v0;
  rp[lane + 64] = b;
}

// ---------------------------------------------------------------------------
// rmsnorm 128-wide f32 rows in place.  4 rows per block (1/wave).
// ---------------------------------------------------------------------------
__global__ __launch_bounds__(256) void rms_rows_k(
    float* __restrict__ x, const float* __restrict__ w)
{
  int r = blockIdx.x * 4 + (threadIdx.x >> 6);
  int lane = threadIdx.x & 63;
  float* rp = x + (size_t)r * 128;
  float a = rp[lane], b = rp[lane + 64];
  float ss = a * a + b * b;
  #pragma unroll
  for (int off = 1; off < 64; off <<= 1) ss += __shfl_xor(ss, off);
  float rn = 1.0f / sqrtf(ss / 128.0f + 1e-6f);
  rp[lane] = a * rn * w[lane];
  rp[lane + 64] = b * rn * w[lane + 64];
}

// ---------------------------------------------------------------------------
// compress with input row-stride ldin: out[n*sn + d*sd]
// ---------------------------------------------------------------------------
__global__ void compress_k(
    const float* __restrict__ c, const float* __restrict__ z, int ldin,
    const float* __restrict__ bias, float* __restrict__ out,
    int D, int sn, int sd)
{
  int idx = blockIdx.x * blockDim.x + threadIdx.x;
  if (idx >= NBLK * D) return;
  int n = idx / D, d = idx % D;
  float zb[16];
  float mx = -INFINITY;
  #pragma unroll
  for (int m = 0; m < 16; ++m) {
    float v = z[(size_t)(n * 16 + m) * ldin + d] + bias[m * D + d];
    zb[m] = v;
    mx = fmaxf(mx, v);
  }
  float s = 0.f;
  #pragma unroll
  for (int m = 0; m < 16; ++m) { zb[m] = expf(zb[m] - mx); s += zb[m]; }
  float acc = 0.f;
  #pragma unroll
  for (int m = 0; m < 16; ++m) acc += zb[m] * c[(size_t)(n * 16 + m) * ldin + d];
  out[(size_t)n * sn + (size_t)d * sd] = acc / s;
}

// ---------------------------------------------------------------------------
// Top-64 per t, fully in-register, one wave per t (4 waves/block).
// ---------------------------------------------------------------------------
__global__ __launch_bounds__(256) void topk_k(
    const float* __restrict__ qi,    // (T, 4, 64)
    const float* __restrict__ wih, int wst,
    const float* __restrict__ kT,    // (64, 512)
    int* __restrict__ top_idx)       // (T, 64)
{
  const int wid = threadIdx.x >> 6;
  const int lane = threadIdx.x & 63;
  const int t = blockIdx.x * 4 + wid;
  __shared__ float qs[4][256];
  for (int i = lane; i < 256; i += 64) qs[wid][i] = qi[(size_t)t * 256 + i];
  float wh[4];
  #pragma unroll
  for (int h = 0; h < 4; ++h) wh[h] = wih[(size_t)t * wst + h];
  __syncthreads();

  float d[4][8] = {};
  for (int cc = 0; cc < 64; ++cc) {
    const float4* kp = (const float4*)(kT + (size_t)cc * 512 + lane * 8);
    float4 k0 = kp[0], k1 = kp[1];
    float kv[8] = {k0.x, k0.y, k0.z, k0.w, k1.x, k1.y, k1.z, k1.w};
    #pragma unroll
    for (int h = 0; h < 4; ++h) {
      float qv = qs[wid][h * 64 + cc];
      #pragma unroll
      for (int s = 0; s < 8; ++s) d[h][s] += qv * kv[s];
    }
  }
  float sc[8];
  #pragma unroll
  for (int s = 0; s < 8; ++s) {
    int n = lane * 8 + s;
    float v = wh[0] * fmaxf(d[0][s], 0.f) + wh[1] * fmaxf(d[1][s], 0.f)
            + wh[2] * fmaxf(d[2][s], 0.f) + wh[3] * fmaxf(d[3][s], 0.f);
    sc[s] = (n * 16 + 15 < t) ? v : -INFINITY;
  }
  float bv = -INFINITY; int bs = 0;
  #pragma unroll
  for (int s = 0; s < 8; ++s) if (sc[s] > bv) { bv = sc[s]; bs = s; }

  int* orow = top_idx + (size_t)t * 64;
  for (int j = 0; j < 64; ++j) {
    float v = bv; int n = lane * 8 + bs;
    #pragma unroll
    for (int off = 32; off >= 1; off >>= 1) {
      float ov = __shfl_xor(v, off);
      int   on = __shfl_xor(n, off);
      if (ov > v || (ov == v && on < n)) { v = ov; n = on; }
    }
    if (lane == 0) orow[j] = (v > -INFINITY) ? n : -1;
    if (v > -INFINITY && (n >> 3) == lane) {
      int rs = n & 7;
      #pragma unroll
      for (int s = 0; s < 8; ++s) sc[s] = (s == rs) ? -INFINITY : sc[s];
      bv = -INFINITY; bs = 0;
      #pragma unroll
      for (int s = 0; s < 8; ++s) if (sc[s] > bv) { bv = sc[s]; bs = s; }
    }
  }
}

// ---------------------------------------------------------------------------
// Sparse attention (q bf16, ckv f32 pre-normalized) -> attn bf16 (writes).
// ---------------------------------------------------------------------------
__global__ __launch_bounds__(256) void sparse_attn_k(
    const u16* __restrict__ q,       // (T, 16, 128) bf16
    const float* __restrict__ nckv,  // (512, 128)
    const int* __restrict__ top_idx, // (T, 64)
    u16* __restrict__ attn)          // (T, 16, 128) bf16
{
  int t = blockIdx.x;
  int tid = threadIdx.x;
  __shared__ float skv[64][132];
  __shared__ float qs[16][132];
  __shared__ float sc[16][65];
  __shared__ int ivals[64];
  if (tid < 64) ivals[tid] = top_idx[(size_t)t * 64 + tid];
  __syncthreads();
  {
    int r = tid >> 2;
    int c0 = (tid & 3) * 32;
    int gi = ivals[r] >= 0 ? ivals[r] : 0;
    #pragma unroll
    for (int i = 0; i < 32; ++i)
      skv[r][c0 + i] = nckv[(size_t)gi * 128 + c0 + i];
  }
  for (int e = tid; e < 2048; e += 256)
    qs[e >> 7][e & 127] = b2f(q[(size_t)t * 2048 + e]);
  __syncthreads();
  for (int e = tid; e < 1024; e += 256) {
    int h = e >> 6, k = e & 63;
    const float4* qa = (const float4*)qs[h];
    const float4* kb = (const float4*)skv[k];
    float d = 0.f;
    #pragma unroll
    for (int i = 0; i < 32; ++i) {
      float4 a = qa[i], b = kb[i];
      d += a.x * b.x + a.y * b.y + a.z * b.z + a.w * b.w;
    }
    sc[h][k] = (ivals[k] >= 0) ? d * SCALE : -INFINITY;
  }
  __syncthreads();
  int h = tid >> 4;
  int d0 = (tid & 15) * 8;
  float m = -INFINITY;
  #pragma unroll
  for (int k = 0; k < 64; ++k) m = fmaxf(m, sc[h][k]);
  float o[8] = {};
  if (m > -INFINITY) {
    float l = 0.f;
    for (int k = 0; k < 64; ++k) {
      float p = expf(sc[h][k] - m);
      l += p;
      #pragma unroll
      for (int i = 0; i < 8; ++i) o[i] += p * skv[k][d0 + i];
    }
    float inv = 1.0f / l;
    #pragma unroll
    for (int i = 0; i < 8; ++i) o[i] *= inv;
  }
  #pragma unroll
  for (int i = 0; i < 8; ++i)
    attn[(size_t)t * 2048 + h * 128 + d0 + i] = f2b(o[i]);
}

// ---------------------------------------------------------------------------
// Sliding-window attention, bf16 MFMA flash.  Block = (64-q tile, head),
// 4 waves x 16 q-rows.  K swizzled in LDS, V transposed+padded, P via
// per-wave LDS.  attn (bf16) +=.
// ---------------------------------------------------------------------------
__global__ __launch_bounds__(256) void win_attn_mfma_k(
    const u16* __restrict__ q,     // (T, 16, 128) bf16
    const float* __restrict__ kv,  // (T, 512) f32: k@0, v@128
    u16* __restrict__ attn)        // (T, 16, 128) bf16 +=
{
  const int qt = blockIdx.x, hh = blockIdx.y;
  const int tid = threadIdx.x;
  const int wid = tid >> 6, lane = tid & 63;
  const int low = lane & 15, grp = lane >> 4;

  __shared__ __align__(16) u16 Ks[64 * 128];
  __shared__ __align__(16) u16 Vt[128 * 72];
  __shared__ __align__(16) u16 Pl[4][16 * 72];

  u16x8 qf[4];
  {
    const u16* qp = q + (size_t)(qt * 64 + wid * 16 + low) * 2048 + hh * 128 + grp * 8;
    #pragma unroll
    for (int kk = 0; kk < 4; ++kk) qf[kk] = *(const u16x8*)(qp + kk * 32);
  }
  f32x4 zero = {0.f, 0.f, 0.f, 0.f};
  f32x4 o[8];
  #pragma unroll
  for (int dt = 0; dt < 8; ++dt) o[dt] = zero;
  float mrow[4] = {-1e30f, -1e30f, -1e30f, -1e30f};
  float lrow[4] = {0.f, 0.f, 0.f, 0.f};

  const int kt0 = qt >= 4 ? qt - 4 : 0;
  const int srow = tid >> 2;
  const int scol = (tid & 3) * 32;
  for (int kt = kt0; kt <= qt; ++kt) {
    __syncthreads();
    {
      const float* gk = kv + (size_t)(kt * 64 + srow) * 512 + scol;
      u16 tmp[32];
      #pragma unroll
      for (int i = 0; i < 32; i += 4) {
        float4 v = *(const float4*)(gk + i);
        tmp[i] = f2b(v.x); tmp[i+1] = f2b(v.y); tmp[i+2] = f2b(v.z); tmp[i+3] = f2b(v.w);
      }
      #pragma unroll
      for (int j = 0; j < 4; ++j) {
        int c = scol + j * 8;
        *(u16x8*)(Ks + srow * 128 + (c ^ ((srow & 7) << 3))) = *(const u16x8*)(tmp + j * 8);
      }
      const float* gv = gk + 128;
      #pragma unroll
      for (int i = 0; i < 32; i += 4) {
        float4 v = *(const float4*)(gv + i);
        Vt[(scol + i + 0) * 72 + srow] = f2b(v.x);
        Vt[(scol + i + 1) * 72 + srow] = f2b(v.y);
        Vt[(scol + i + 2) * 72 + srow] = f2b(v.z);
        Vt[(scol + i + 3) * 72 + srow] = f2b(v.w);
      }
    }
    __syncthreads();
    f32x4 s[4];
    #pragma unroll
    for (int n = 0; n < 4; ++n) {
      s[n] = zero;
      int krow = n * 16 + low;
      #pragma unroll
      for (int kk = 0; kk < 4; ++kk) {
        u16x8 kf = *(const u16x8*)(Ks + krow * 128 + ((kk * 32 + grp * 8) ^ ((krow & 7) << 3)));
        mfma16(s[n], qf[kk], kf);
      }
    }
    asm volatile("s_nop 7\n\ts_nop 7");
    const int qg = qt * 64 + wid * 16 + grp * 4;
    #pragma unroll
    for (int n = 0; n < 4; ++n) {
      int kg = kt * 64 + n * 16 + low;
      #pragma unroll
      for (int r = 0; r < 4; ++r) {
        bool ok = (kg <= qg + r) && (kg > qg + r - 256);
        s[n][r] = ok ? s[n][r] * SCALE : -1e30f;
      }
    }
    float p[4][4];
    #pragma unroll
    for (int r = 0; r < 4; ++r) {
      float rm = fmaxf(fmaxf(s[0][r], s[1][r]), fmaxf(s[2][r], s[3][r]));
      rm = fmaxf(rm, __shfl_xor(rm, 1));
      rm = fmaxf(rm, __shfl_xor(rm, 2));
      rm = fmaxf(rm, __shfl_xor(rm, 4));
      rm = fmaxf(rm, __shfl_xor(rm, 8));
      float nm = fmaxf(mrow[r], rm);
      float f = __expf(mrow[r] - nm);
      mrow[r] = nm;
      float ps = 0.f;
      #pragma unroll
      for (int n = 0; n < 4; ++n) { p[n][r] = __expf(s[n][r] - nm); ps += p[n][r]; }
      ps += __shfl_xor(ps, 1); ps += __shfl_xor(ps, 2);
      ps += __shfl_xor(ps, 4); ps += __shfl_xor(ps, 8);
      lrow[r] = lrow[r] * f + ps;
      #pragma unroll
      for (int dt = 0; dt < 8; ++dt) o[dt][r] *= f;
    }
    u16* pw = Pl[wid];
    #pragma unroll
    for (int n = 0; n < 4; ++n)
      #pragma unroll
      for (int r = 0; r < 4; ++r)
        pw[(grp * 4 + r) * 72 + n * 16 + low] = f2b(p[n][r]);
    #pragma unroll
    for (int kk2 = 0; kk2 < 2; ++kk2) {
      u16x8 pa = *(const u16x8*)(pw + low * 72 + kk2 * 32 + grp * 8);
      #pragma unroll
      for (int dt = 0; dt < 8; ++dt) {
        u16x8 vf = *(const u16x8*)(Vt + (dt * 16 + low) * 72 + kk2 * 32 + grp * 8);
        mfma16(o[dt], pa, vf);
      }
    }
  }
  asm volatile("s_nop 7\n\ts_nop 7");
  float linv[4];
  #pragma unroll
  for (int r = 0; r < 4; ++r) linv[r] = 1.0f / lrow[r];
  u16* ap = attn + (size_t)(qt * 64 + wid * 16 + grp * 4) * 2048 + hh * 128 + low;
  #pragma unroll
  for (int r = 0; r < 4; ++r)
    #pragma unroll
    for (int dt = 0; dt < 8; ++dt) {
      size_t idx = (size_t)r * 2048 + dt * 16;
      ap[idx] = f2b(b2f(ap[idx]) + o[dt][r] * linv[r]);
    }
}

// ---------------------------------------------------------------------------
extern "C" void kernel_launch(void* const* d_in, const int* in_sizes, int n_in,
                              void* d_out, int out_size, void* d_ws, size_t ws_size,
                              hipStream_t stream)
{
  const float* h        = (const float*)d_in[0];
  const float* w_qc     = (const float*)d_in[1];
  const float* w_qup    = (const float*)d_in[2];
  const float* kvc_w    = (const float*)d_in[3];
  const float* kvc_wz   = (const float*)d_in[4];
  const float* kvc_bias = (const float*)d_in[5];
  const float* k_proj_w = (const float*)d_in[6];
  const float* v_proj_w = (const float*)d_in[7];
  const float* idx_c_w  = (const float*)d_in[8];
  const float* idx_c_wz = (const float*)d_in[9];
  const float* idx_c_bias = (const float*)d_in[10];
  const float* w_dq     = (const float*)d_in[11];
  const float* w_iuq    = (const float*)d_in[12];
  const float* w_w      = (const float*)d_in[13];
  const float* q_norm_w = (const float*)d_in[14];
  const float* k_norm_w = (const float*)d_in[15];
  const float* group_w  = (const float*)d_in[16];
  const float* final_w  = (const float*)d_in[17];
  float* out = (float*)d_out;

  float* ws = (float*)d_ws;
  size_t off = 0;
  auto alloc = [&](size_t nfloats) { float* p = ws + off; off += nfloats; return p; };
  float* cosT  = alloc((size_t)T_LEN * 32);
  float* sinT  = alloc((size_t)T_LEN * 32);
  u16* qb      = (u16*)alloc((size_t)T_LEN * 1024);
  u16* attnb   = (u16*)alloc((size_t)T_LEN * 1024);
  u16* hb      = (u16*)alloc((size_t)T_LEN * 1024);
  float* kvout = alloc((size_t)T_LEN * 512);
  float* ibuf  = alloc((size_t)T_LEN * 228);
  float* kT    = alloc((size_t)64 * NBLK);
  float* ckv   = alloc((size_t)NBLK * 128);
  float* qib   = alloc((size_t)T_LEN * 256);
  int*   topi  = (int*)alloc((size_t)T_LEN * 64);
  u16* w_qcT   = (u16*)alloc((size_t)512 * 1024);
  u16* w_qupT  = (u16*)alloc((size_t)2048 * 256);
  u16* kvT     = (u16*)alloc((size_t)512 * 1024);
  u16* gwT     = (u16*)alloc((size_t)4 * 512 * 256);
  u16* fwT     = (u16*)alloc((size_t)2048 * 1024);
  float* part  = alloc((size_t)4 * T_LEN * NIDX);     // split-K partials
  float* Bcat  = (float*)attnb;                       // 2048 x 196 f32
  u16* hq1b    = (u16*)((float*)attnb + 524288);
  u16* og      = qb;

  rope_cs_k<<<(T_LEN * 32 + 255) / 256, 256, 0, stream>>>(cosT, sinT);
  castk<<<(T_LEN * 2048 / 4 + 255) / 256, 256, 0, stream>>>(h, hb, T_LEN * 2048 / 4);
  tcast_k<<<dim3(16, 64), 256, 0, stream>>>(w_qc, w_qcT, 2048, 512);
  tcast_k<<<dim3(64, 16), 256, 0, stream>>>(w_qup, w_qupT, 512, 2048);
  tcast_k<<<dim3(4, 64), 256, 0, stream>>>(k_proj_w, kvT + (size_t)0 * 128 * 2048, 2048, 128);
  tcast_k<<<dim3(4, 64), 256, 0, stream>>>(v_proj_w, kvT + (size_t)1 * 128 * 2048, 2048, 128);
  tcast_k<<<dim3(4, 64), 256, 0, stream>>>(kvc_w,    kvT + (size_t)2 * 128 * 2048, 2048, 128);
  tcast_k<<<dim3(4, 64), 256, 0, stream>>>(kvc_wz,   kvT + (size_t)3 * 128 * 2048, 2048, 128);
  for (int g = 0; g < 4; ++g)
    tcast_k<<<dim3(16, 16), 256, 0, stream>>>(group_w + (size_t)g * 512 * 512,
                                              gwT + (size_t)g * 512 * 512, 512, 512);
  tcast_k<<<dim3(64, 64), 256, 0, stream>>>(final_w, fwT, 2048, 2048);
  concat_idx_k<<<(2048 * NIDX + 255) / 256, 256, 0, stream>>>(idx_c_w, idx_c_wz, w_dq, w_w, Bcat);

  // q chain (bf16 MFMA)
  bgemm_k<1><<<dim3(4, 64), 256, 0, stream>>>(hb, 2048, w_qcT, 2048, hq1b, 512, 2048);
  bgemm_k<1><<<dim3(16, 64), 256, 0, stream>>>(hq1b, 512, w_qupT, 512, qb, 2048, 512);
  q_rope_norm_k<<<T_LEN * 4, 256, 0, stream>>>(qb, cosT, sinT, q_norm_w);

  // fused k|v|kvc projections
  bgemm_k<0><<<dim3(4, 64), 256, 0, stream>>>(hb, 2048, kvT, 2048, kvout, 512, 2048);
  k_norm_rope_k<<<T_LEN / 4, 256, 0, stream>>>(kvout, cosT, sinT, k_norm_w);
  compress_k<<<(NBLK * 128 + 255) / 256, 256, 0, stream>>>(
      kvout + 256, kvout + 384, 512, kvc_bias, ckv, 128, 128, 1);
  rms_rows_k<<<NBLK / 4, 256, 0, stream>>>(ckv, k_norm_w);

  // index path (f32 exact for selection stability; split-K for occupancy)
  sgemm_splitk_k<<<dim3(4, 128, 4), 256, 0, stream>>>(h, HID, Bcat, NIDX, part, NIDX, T_LEN, NIDX, 512);
  reduce4_k<<<(T_LEN * NIDX + 255) / 256, 256, 0, stream>>>(part, NIDX, ibuf, 228, T_LEN);
  compress_k<<<(NBLK * 64 + 255) / 256, 256, 0, stream>>>(
      ibuf, ibuf + 64, 228, idx_c_bias, kT, 64, 1, NBLK);
  sgemm_k<<<dim3(4, 128), 256, 0, stream>>>(ibuf + 128, 228, w_iuq, 256, qib, 256, T_LEN, 256, 64);
  topk_k<<<T_LEN / 4, 256, 0, stream>>>(qib, ibuf + 192, 228, kT, topi);

  // attention
  sparse_attn_k<<<T_LEN, 256, 0, stream>>>(qb, ckv, topi, attnb);
  win_attn_mfma_k<<<dim3(T_LEN / 64, 16), 256, 0, stream>>>(qb, kvout, attnb);

  // output projections (bf16 MFMA)
  for (int g = 0; g < 4; ++g)
    bgemm_k<1><<<dim3(4, 64), 256, 0, stream>>>(
        attnb + (size_t)g * 512, 2048, gwT + (size_t)g * 512 * 512, 512,
        og + (size_t)g * 512, 2048, 512);
  bgemm_k<0><<<dim3(16, 64), 256, 0, stream>>>(og, 2048, fwT, 2048, out, 2048, 2048);
}

// Round 6
// 946.467 us; speedup vs baseline: 10.3602x; 1.1206x over previous
//
#include <hip/hip_runtime.h>
#include <math.h>

#define T_LEN 8192
#define HID   2048
#define NHEAD 16
#define HD    128
#define NBLK  512
#define NIDX  196                    // 64+64+64+4 used index-path columns
#define SCALE 0.08838834764831845f   // 1/sqrt(128)

typedef unsigned short u16;
typedef unsigned short u16x8 __attribute__((ext_vector_type(8)));
typedef float f32x4 __attribute__((ext_vector_type(4)));

// ---- bf16 <-> f32 via bit ops (RNE) ----
__device__ __forceinline__ u16 f2b(float f) {
  unsigned int u = __float_as_uint(f);
  return (u16)((u + 0x7fffu + ((u >> 16) & 1u)) >> 16);
}
__device__ __forceinline__ float b2f(u16 s) {
  return __uint_as_float(((unsigned int)s) << 16);
}

// ---- async global->LDS, 16B per lane (dest must be wave-linear) ----
__device__ __forceinline__ void gload16(const u16* g, u16* l) {
  __builtin_amdgcn_global_load_lds(
      (__attribute__((address_space(1))) void*)(uintptr_t)g,
      (__attribute__((address_space(3))) void*)(unsigned int)(uintptr_t)l,
      16, 0, 0);
}

// ---- MFMA 16x16x32 bf16 via inline asm (D/C tied) ----
__device__ __forceinline__ void mfma16(f32x4& d, u16x8 a, u16x8 b) {
  asm("v_mfma_f32_16x16x32_bf16 %0, %1, %2, %0" : "+v"(d) : "v"(a), "v"(b));
}

// ---------------------------------------------------------------------------
// bf16 MFMA GEMM: C[M,N] = A[M,K] @ Bt[N,K]^T.  m97 structure, 128x128 tile.
// ---------------------------------------------------------------------------
template<int OUT_BF16>
__global__ __launch_bounds__(256) void bgemm_k(
    const u16* __restrict__ A, int lda,
    const u16* __restrict__ Bt, int ldb,
    void* __restrict__ Cp, int ldc, int K)
{
  __shared__ __align__(16) u16 Al[128 * 32];
  __shared__ __align__(16) u16 Bl[128 * 32];
  const int tid = threadIdx.x;
  const int lane = tid & 63;
  const int bm = blockIdx.y * 128;
  const int bn = blockIdx.x * 128;
  const int wr = ((tid >> 6) >> 1) * 64;
  const int wc = ((tid >> 6) & 1) * 64;
  const int r0 = tid >> 2;
  const int c0 = (tid & 3) * 8;
  const u16* ga0 = A  + (size_t)(bm + r0) * lda + c0;
  const u16* ga1 = ga0 + (size_t)64 * lda;
  const u16* gb0 = Bt + (size_t)(bn + r0) * ldb + c0;
  const u16* gb1 = gb0 + (size_t)64 * ldb;
  u16* la0 = Al + tid * 8;
  u16* la1 = Al + (tid + 256) * 8;
  u16* lb0 = Bl + tid * 8;
  u16* lb1 = Bl + (tid + 256) * 8;

  f32x4 zero = {0.f, 0.f, 0.f, 0.f};
  f32x4 acc[4][4];
  #pragma unroll
  for (int m = 0; m < 4; ++m)
    #pragma unroll
    for (int n = 0; n < 4; ++n) acc[m][n] = zero;

  const int ar = wr + (lane & 15);
  const int br = wc + (lane & 15);
  const int ko = (lane >> 4) * 8;

  for (int k0 = 0; k0 < K; k0 += 32) {
    gload16(ga0 + k0, la0);
    gload16(ga1 + k0, la1);
    gload16(gb0 + k0, lb0);
    gload16(gb1 + k0, lb1);
    __syncthreads();
    u16x8 af[4], bfr[4];
    #pragma unroll
    for (int m = 0; m < 4; ++m)
      af[m] = *(const u16x8*)(Al + (size_t)(ar + m * 16) * 32 + ko);
    #pragma unroll
    for (int n = 0; n < 4; ++n)
      bfr[n] = *(const u16x8*)(Bl + (size_t)(br + n * 16) * 32 + ko);
    #pragma unroll
    for (int m = 0; m < 4; ++m)
      #pragma unroll
      for (int n = 0; n < 4; ++n) mfma16(acc[m][n], af[m], bfr[n]);
    __syncthreads();
  }
  asm volatile("s_nop 7\n\ts_nop 7");
  const int er = (lane >> 4) * 4;
  const int ec = lane & 15;
  #pragma unroll
  for (int m = 0; m < 4; ++m)
    #pragma unroll
    for (int n = 0; n < 4; ++n)
      #pragma unroll
      for (int r = 0; r < 4; ++r) {
        size_t idx = (size_t)(bm + wr + m * 16 + er + r) * ldc + (bn + wc + n * 16 + ec);
        if (OUT_BF16) ((u16*)Cp)[idx] = f2b(acc[m][n][r]);
        else          ((float*)Cp)[idx] = acc[m][n][r];
      }
}

// ---------------------------------------------------------------------------
// Fused qc|kv projection GEMM: A = hb (8192x2048), Bt = [w_qcT(512) ; kvT(512)]
// (1024x2048).  Cols 0-511 -> Cq bf16 (ld 512); cols 512-1023 -> Ckv f32 (ld 512).
// ---------------------------------------------------------------------------
__global__ __launch_bounds__(256) void bgemm_qckv_k(
    const u16* __restrict__ A, const u16* __restrict__ Bt,
    u16* __restrict__ Cq, float* __restrict__ Ckv)
{
  __shared__ __align__(16) u16 Al[128 * 32];
  __shared__ __align__(16) u16 Bl[128 * 32];
  const int tid = threadIdx.x;
  const int lane = tid & 63;
  const int bm = blockIdx.y * 128;
  const int bn = blockIdx.x * 128;
  const int wr = ((tid >> 6) >> 1) * 64;
  const int wc = ((tid >> 6) & 1) * 64;
  const int r0 = tid >> 2;
  const int c0 = (tid & 3) * 8;
  const u16* ga0 = A  + (size_t)(bm + r0) * 2048 + c0;
  const u16* ga1 = ga0 + (size_t)64 * 2048;
  const u16* gb0 = Bt + (size_t)(bn + r0) * 2048 + c0;
  const u16* gb1 = gb0 + (size_t)64 * 2048;
  u16* la0 = Al + tid * 8;
  u16* la1 = Al + (tid + 256) * 8;
  u16* lb0 = Bl + tid * 8;
  u16* lb1 = Bl + (tid + 256) * 8;

  f32x4 zero = {0.f, 0.f, 0.f, 0.f};
  f32x4 acc[4][4];
  #pragma unroll
  for (int m = 0; m < 4; ++m)
    #pragma unroll
    for (int n = 0; n < 4; ++n) acc[m][n] = zero;

  const int ar = wr + (lane & 15);
  const int br = wc + (lane & 15);
  const int ko = (lane >> 4) * 8;

  for (int k0 = 0; k0 < 2048; k0 += 32) {
    gload16(ga0 + k0, la0);
    gload16(ga1 + k0, la1);
    gload16(gb0 + k0, lb0);
    gload16(gb1 + k0, lb1);
    __syncthreads();
    u16x8 af[4], bfr[4];
    #pragma unroll
    for (int m = 0; m < 4; ++m)
      af[m] = *(const u16x8*)(Al + (size_t)(ar + m * 16) * 32 + ko);
    #pragma unroll
    for (int n = 0; n < 4; ++n)
      bfr[n] = *(const u16x8*)(Bl + (size_t)(br + n * 16) * 32 + ko);
    #pragma unroll
    for (int m = 0; m < 4; ++m)
      #pragma unroll
      for (int n = 0; n < 4; ++n) mfma16(acc[m][n], af[m], bfr[n]);
    __syncthreads();
  }
  asm volatile("s_nop 7\n\ts_nop 7");
  const int er = (lane >> 4) * 4;
  const int ec = lane & 15;
  if (bn < 512) {
    #pragma unroll
    for (int m = 0; m < 4; ++m)
      #pragma unroll
      for (int n = 0; n < 4; ++n)
        #pragma unroll
        for (int r = 0; r < 4; ++r)
          Cq[(size_t)(bm + wr + m * 16 + er + r) * 512 + (bn + wc + n * 16 + ec)]
              = f2b(acc[m][n][r]);
  } else {
    #pragma unroll
    for (int m = 0; m < 4; ++m)
      #pragma unroll
      for (int n = 0; n < 4; ++n)
        #pragma unroll
        for (int r = 0; r < 4; ++r)
          Ckv[(size_t)(bm + wr + m * 16 + er + r) * 512 + (bn - 512 + wc + n * 16 + ec)]
              = acc[m][n][r];
  }
}

// ---------------------------------------------------------------------------
// Fused group projection: z = group.  A = attnb + z*512 (ld 2048), K=512,
// Bt = gwT + z*512*512, C = og + z*512 (ld 2048) bf16.
// ---------------------------------------------------------------------------
__global__ __launch_bounds__(256) void bgemm_group_k(
    const u16* __restrict__ Ab, const u16* __restrict__ gw,
    u16* __restrict__ Cb)
{
  __shared__ __align__(16) u16 Al[128 * 32];
  __shared__ __align__(16) u16 Bl[128 * 32];
  const int tid = threadIdx.x;
  const int lane = tid & 63;
  const int bm = blockIdx.y * 128;
  const int bn = blockIdx.x * 128;
  const int g  = blockIdx.z;
  const u16* A  = Ab + (size_t)g * 512;
  const u16* Bt = gw + (size_t)g * 512 * 512;
  u16* C = Cb + (size_t)g * 512;
  const int wr = ((tid >> 6) >> 1) * 64;
  const int wc = ((tid >> 6) & 1) * 64;
  const int r0 = tid >> 2;
  const int c0 = (tid & 3) * 8;
  const u16* ga0 = A  + (size_t)(bm + r0) * 2048 + c0;
  const u16* ga1 = ga0 + (size_t)64 * 2048;
  const u16* gb0 = Bt + (size_t)(bn + r0) * 512 + c0;
  const u16* gb1 = gb0 + (size_t)64 * 512;
  u16* la0 = Al + tid * 8;
  u16* la1 = Al + (tid + 256) * 8;
  u16* lb0 = Bl + tid * 8;
  u16* lb1 = Bl + (tid + 256) * 8;

  f32x4 zero = {0.f, 0.f, 0.f, 0.f};
  f32x4 acc[4][4];
  #pragma unroll
  for (int m = 0; m < 4; ++m)
    #pragma unroll
    for (int n = 0; n < 4; ++n) acc[m][n] = zero;

  const int ar = wr + (lane & 15);
  const int br = wc + (lane & 15);
  const int ko = (lane >> 4) * 8;

  for (int k0 = 0; k0 < 512; k0 += 32) {
    gload16(ga0 + k0, la0);
    gload16(ga1 + k0, la1);
    gload16(gb0 + k0, lb0);
    gload16(gb1 + k0, lb1);
    __syncthreads();
    u16x8 af[4], bfr[4];
    #pragma unroll
    for (int m = 0; m < 4; ++m)
      af[m] = *(const u16x8*)(Al + (size_t)(ar + m * 16) * 32 + ko);
    #pragma unroll
    for (int n = 0; n < 4; ++n)
      bfr[n] = *(const u16x8*)(Bl + (size_t)(br + n * 16) * 32 + ko);
    #pragma unroll
    for (int m = 0; m < 4; ++m)
      #pragma unroll
      for (int n = 0; n < 4; ++n) mfma16(acc[m][n], af[m], bfr[n]);
    __syncthreads();
  }
  asm volatile("s_nop 7\n\ts_nop 7");
  const int er = (lane >> 4) * 4;
  const int ec = lane & 15;
  #pragma unroll
  for (int m = 0; m < 4; ++m)
    #pragma unroll
    for (int n = 0; n < 4; ++n)
      #pragma unroll
      for (int r = 0; r < 4; ++r)
        C[(size_t)(bm + wr + m * 16 + er + r) * 2048 + (bn + wc + n * 16 + ec)]
            = f2b(acc[m][n][r]);
}

// ---------------------------------------------------------------------------
// f32 GEMM with split-K, vectorized LDS reads (16B-aligned padded tiles).
// blockIdx.z selects K-chunk; writes partials P[z][M][ldc].
// ---------------------------------------------------------------------------
__global__ __launch_bounds__(256) void sgemm_splitk_k(
    const float* __restrict__ A, int lda,
    const float* __restrict__ B, int ldb,
    float* __restrict__ P, int ldc,
    int M, int N, int kchunk)
{
  __shared__ __align__(16) float As[16][68];
  __shared__ __align__(16) float Bs[16][68];
  const int bm = blockIdx.y * 64;
  const int bn = blockIdx.x * 64;
  const int kb = blockIdx.z * kchunk;
  float* C = P + (size_t)blockIdx.z * M * ldc;
  const int tid = threadIdx.x;
  const int tx = tid & 15;
  const int ty = tid >> 4;
  float acc[4][4] = {};
  for (int k0 = 0; k0 < kchunk; k0 += 16) {
    #pragma unroll
    for (int i = 0; i < 4; ++i) {
      int f = tid + i * 256;
      int r = f >> 4, c = f & 15;
      float v = 0.f;
      int gr = bm + r, gc = kb + k0 + c;
      if (gr < M) v = A[(size_t)gr * lda + gc];
      As[c][r] = v;
    }
    #pragma unroll
    for (int i = 0; i < 4; ++i) {
      int f = tid + i * 256;
      int r = f >> 6, c = f & 63;
      float v = 0.f;
      int gr = kb + k0 + r, gc = bn + c;
      if (gc < N) v = B[(size_t)gr * ldb + gc];
      Bs[r][c] = v;
    }
    __syncthreads();
    #pragma unroll
    for (int kk = 0; kk < 16; ++kk) {
      float4 a = *(const float4*)&As[kk][ty * 4];
      float4 b = *(const float4*)&Bs[kk][tx * 4];
      float av[4] = {a.x, a.y, a.z, a.w};
      float bv[4] = {b.x, b.y, b.z, b.w};
      #pragma unroll
      for (int i = 0; i < 4; ++i)
        #pragma unroll
        for (int j = 0; j < 4; ++j) acc[i][j] += av[i] * bv[j];
    }
    __syncthreads();
  }
  #pragma unroll
  for (int i = 0; i < 4; ++i) {
    int gr = bm + ty * 4 + i;
    if (gr >= M) continue;
    #pragma unroll
    for (int j = 0; j < 4; ++j) {
      int gc = bn + tx * 4 + j;
      if (gc < N) C[(size_t)gr * ldc + gc] = acc[i][j];
    }
  }
}

// ---- sum 4 split-K partials [4][M][ldp] -> out[M][ldo] ----
__global__ void reduce4_k(const float* __restrict__ P, int ldp,
                          float* __restrict__ o, int ldo, int M)
{
  int i = blockIdx.x * 256 + threadIdx.x;
  if (i >= M * ldp) return;
  int r = i / ldp, c = i % ldp;
  size_t st = (size_t)M * ldp;
  float v = P[i] + P[i + st] + P[i + 2 * st] + P[i + 3 * st];
  o[(size_t)r * ldo + c] = v;
}

// ---------------------------------------------------------------------------
// Generic tiled f32 GEMM (small-K qib GEMM), vectorized LDS reads.
// ---------------------------------------------------------------------------
__global__ __launch_bounds__(256) void sgemm_k(
    const float* __restrict__ A, int lda,
    const float* __restrict__ B, int ldb,
    float* __restrict__ C, int ldc,
    int M, int N, int K)
{
  __shared__ __align__(16) float As[16][68];
  __shared__ __align__(16) float Bs[16][68];
  const int bm = blockIdx.y * 64;
  const int bn = blockIdx.x * 64;
  const int tid = threadIdx.x;
  const int tx = tid & 15;
  const int ty = tid >> 4;
  float acc[4][4] = {};
  for (int k0 = 0; k0 < K; k0 += 16) {
    #pragma unroll
    for (int i = 0; i < 4; ++i) {
      int f = tid + i * 256;
      int r = f >> 4, c = f & 15;
      float v = 0.f;
      int gr = bm + r, gc = k0 + c;
      if (gr < M && gc < K) v = A[(size_t)gr * lda + gc];
      As[c][r] = v;
    }
    #pragma unroll
    for (int i = 0; i < 4; ++i) {
      int f = tid + i * 256;
      int r = f >> 6, c = f & 63;
      float v = 0.f;
      int gr = k0 + r, gc = bn + c;
      if (gr < K && gc < N) v = B[(size_t)gr * ldb + gc];
      Bs[r][c] = v;
    }
    __syncthreads();
    #pragma unroll
    for (int kk = 0; kk < 16; ++kk) {
      float4 a = *(const float4*)&As[kk][ty * 4];
      float4 b = *(const float4*)&Bs[kk][tx * 4];
      float av[4] = {a.x, a.y, a.z, a.w};
      float bv[4] = {b.x, b.y, b.z, b.w};
      #pragma unroll
      for (int i = 0; i < 4; ++i)
        #pragma unroll
        for (int j = 0; j < 4; ++j) acc[i][j] += av[i] * bv[j];
    }
    __syncthreads();
  }
  #pragma unroll
  for (int i = 0; i < 4; ++i) {
    int gr = bm + ty * 4 + i;
    if (gr >= M) continue;
    #pragma unroll
    for (int j = 0; j < 4; ++j) {
      int gc = bn + tx * 4 + j;
      if (gc < N) C[(size_t)gr * ldc + gc] = acc[i][j];
    }
  }
}

// ---------------------------------------------------------------------------
// f32 -> bf16 cast (4 elems/thread)
// ---------------------------------------------------------------------------
__global__ void castk(const float* __restrict__ in, u16* __restrict__ out, int n4)
{
  int i = blockIdx.x * 256 + threadIdx.x;
  if (i >= n4) return;
  float4 v = ((const float4*)in)[i];
  unsigned int lo = (unsigned int)f2b(v.x) | ((unsigned int)f2b(v.y) << 16);
  unsigned int hi = (unsigned int)f2b(v.z) | ((unsigned int)f2b(v.w) << 16);
  ((uint2*)out)[i] = make_uint2(lo, hi);
}

// ---------------------------------------------------------------------------
// transpose + cast: in f32 [R][C] -> out bf16 [C][R]
// ---------------------------------------------------------------------------
__global__ __launch_bounds__(256) void tcast_k(
    const float* __restrict__ in, u16* __restrict__ outT, int R, int C)
{
  __shared__ float t[32][33];
  int bc = blockIdx.x * 32, br = blockIdx.y * 32;
  int lx = threadIdx.x & 31, ly = threadIdx.x >> 5;
  #pragma unroll
  for (int i = 0; i < 32; i += 8) {
    int r = br + ly + i, c = bc + lx;
    t[ly + i][lx] = (r < R && c < C) ? in[(size_t)r * C + c] : 0.f;
  }
  __syncthreads();
  #pragma unroll
  for (int i = 0; i < 32; i += 8) {
    int c = bc + ly + i, r = br + lx;
    if (c < C && r < R) outT[(size_t)c * R + r] = f2b(t[lx][ly + i]);
  }
}

// ---------------------------------------------------------------------------
// Concat the 4 index-path weights into Bcat f32 (2048 x 196)
// ---------------------------------------------------------------------------
__global__ void concat_idx_k(const float* __restrict__ a, const float* __restrict__ b,
                             const float* __restrict__ c, const float* __restrict__ d,
                             float* __restrict__ o)
{
  int i = blockIdx.x * 256 + threadIdx.x;
  if (i >= 2048 * NIDX) return;
  int r = i / NIDX, col = i % NIDX;
  float v = (col < 64)  ? a[r * 64 + col]
          : (col < 128) ? b[r * 64 + col - 64]
          : (col < 192) ? c[r * 64 + col - 128]
          :               d[r * 4 + col - 192];
  o[i] = v;
}

// ---------------------------------------------------------------------------
// RoPE cos/sin tables: (T, 32) each.
// ---------------------------------------------------------------------------
__global__ void rope_cs_k(float* __restrict__ ct, float* __restrict__ st)
{
  int idx = blockIdx.x * blockDim.x + threadIdx.x;
  if (idx >= T_LEN * 32) return;
  int t = idx >> 5, i = idx & 31;
  float inv = powf(10000.0f, -(float)(2 * i) / 64.0f);
  float ang = (float)t * inv;
  ct[idx] = cosf(ang);
  st[idx] = sinf(ang);
}

// ---------------------------------------------------------------------------
// q (bf16, row = t*16+h): rope then rmsnorm, in place. 4 rows/block (1/wave).
// ---------------------------------------------------------------------------
__global__ __launch_bounds__(256) void q_rope_norm_k(
    u16* __restrict__ q, const float* __restrict__ ct,
    const float* __restrict__ st, const float* __restrict__ w)
{
  int wid = threadIdx.x >> 6;
  int row = blockIdx.x * 4 + wid;
  int t = row >> 4;
  int lane = threadIdx.x & 63;
  __shared__ float ls[4][128];
  u16* rp = q + (size_t)row * 128;
  ls[wid][lane] = b2f(rp[lane]);
  ls[wid][lane + 64] = b2f(rp[lane + 64]);
  __syncthreads();
  float v0;
  if (lane < 32) {
    float c = ct[t * 32 + lane], s = st[t * 32 + lane];
    v0 = ls[wid][lane] * c - ls[wid][lane + 32] * s;
  } else {
    int i = lane - 32;
    float c = ct[t * 32 + i], s = st[t * 32 + i];
    v0 = ls[wid][i] * s + ls[wid][lane] * c;
  }
  float v1 = ls[wid][lane + 64];
  float ss = v0 * v0 + v1 * v1;
  #pragma unroll
  for (int off = 1; off < 64; off <<= 1) ss += __shfl_xor(ss, off);
  float rn = 1.0f / sqrtf(ss / 128.0f + 1e-6f);
  rp[lane] = f2b(v0 * rn * w[lane]);
  rp[lane + 64] = f2b(v1 * rn * w[lane + 64]);
}

// ---------------------------------------------------------------------------
// sw_k inside kvout (f32, row stride 512, cols 0..127): rmsnorm then rope.
// ---------------------------------------------------------------------------
__global__ __launch_bounds__(256) void k_norm_rope_k(
    float* __restrict__ kv, const float* __restrict__ ct,
    const float* __restrict__ st, const float* __restrict__ w)
{
  int wid = threadIdx.x >> 6;
  int t = blockIdx.x * 4 + wid;
  int lane = threadIdx.x & 63;
  __shared__ float ls[4][128];
  float* rp = kv + (size_t)t * 512;
  float a = rp[lane], b = rp[lane + 64];
  float ss = a * a + b * b;
  #pragma unroll
  for (int off = 1; off < 64; off <<= 1) ss += __shfl_xor(ss, off);
  float rn = 1.0f / sqrtf(ss / 128.0f + 1e-6f);
  a *= rn * w[lane];
  b *= rn * w[lane + 64];
  ls[wid][lane] = a;
  ls[wid][lane + 64] = b;
  __syncthreads();
  float v0;
  if (lane < 32) {
    float c = ct[t * 32 + lane], s = st[t * 32 + lane];
    v0 = ls[wid][lane] * c - ls[wid][lane + 32] * s;
  } else {
    int i = lane - 32;
    float c = ct[t * 32 + i], s = st[t * 32 + i];
    v0 = ls[wid][i] * s + ls[wid][lane] * c;
  }
  rp[lane] = v0;
  rp[lane + 64] = b;
}

// ---------------------------------------------------------------------------
// rmsnorm 128-wide f32 rows in place.  4 rows per block (1/wave).
// ---------------------------------------------------------------------------
__global__ __launch_bounds__(256) void rms_rows_k(
    float* __restrict__ x, const float* __restrict__ w)
{
  int r = blockIdx.x * 4 + (threadIdx.x >> 6);
  int lane = threadIdx.x & 63;
  float* rp = x + (size_t)r * 128;
  float a = rp[lane], b = rp[lane + 64];
  float ss = a * a + b * b;
  #pragma unroll
  for (int off = 1; off < 64; off <<= 1) ss += __shfl_xor(ss, off);
  float rn = 1.0f / sqrtf(ss / 128.0f + 1e-6f);
  rp[lane] = a * rn * w[lane];
  rp[lane + 64] = b * rn * w[lane + 64];
}

// ---------------------------------------------------------------------------
// compress with input row-stride ldin: out[n*sn + d*sd]
// ---------------------------------------------------------------------------
__global__ void compress_k(
    const float* __restrict__ c, const float* __restrict__ z, int ldin,
    const float* __restrict__ bias, float* __restrict__ out,
    int D, int sn, int sd)
{
  int idx = blockIdx.x * blockDim.x + threadIdx.x;
  if (idx >= NBLK * D) return;
  int n = idx / D, d = idx % D;
  float zb[16];
  float mx = -INFINITY;
  #pragma unroll
  for (int m = 0; m < 16; ++m) {
    float v = z[(size_t)(n * 16 + m) * ldin + d] + bias[m * D + d];
    zb[m] = v;
    mx = fmaxf(mx, v);
  }
  float s = 0.f;
  #pragma unroll
  for (int m = 0; m < 16; ++m) { zb[m] = expf(zb[m] - mx); s += zb[m]; }
  float acc = 0.f;
  #pragma unroll
  for (int m = 0; m < 16; ++m) acc += zb[m] * c[(size_t)(n * 16 + m) * ldin + d];
  out[(size_t)n * sn + (size_t)d * sd] = acc / s;
}

// ---------------------------------------------------------------------------
// Top-64 per t, fully in-register, one wave per t (4 waves/block).
// ---------------------------------------------------------------------------
__global__ __launch_bounds__(256) void topk_k(
    const float* __restrict__ qi,    // (T, 4, 64)
    const float* __restrict__ wih, int wst,
    const float* __restrict__ kT,    // (64, 512)
    int* __restrict__ top_idx)       // (T, 64)
{
  const int wid = threadIdx.x >> 6;
  const int lane = threadIdx.x & 63;
  const int t = blockIdx.x * 4 + wid;
  __shared__ float qs[4][256];
  for (int i = lane; i < 256; i += 64) qs[wid][i] = qi[(size_t)t * 256 + i];
  float wh[4];
  #pragma unroll
  for (int h = 0; h < 4; ++h) wh[h] = wih[(size_t)t * wst + h];
  __syncthreads();

  float d[4][8] = {};
  for (int cc = 0; cc < 64; ++cc) {
    const float4* kp = (const float4*)(kT + (size_t)cc * 512 + lane * 8);
    float4 k0 = kp[0], k1 = kp[1];
    float kv[8] = {k0.x, k0.y, k0.z, k0.w, k1.x, k1.y, k1.z, k1.w};
    #pragma unroll
    for (int h = 0; h < 4; ++h) {
      float qv = qs[wid][h * 64 + cc];
      #pragma unroll
      for (int s = 0; s < 8; ++s) d[h][s] += qv * kv[s];
    }
  }
  float sc[8];
  #pragma unroll
  for (int s = 0; s < 8; ++s) {
    int n = lane * 8 + s;
    float v = wh[0] * fmaxf(d[0][s], 0.f) + wh[1] * fmaxf(d[1][s], 0.f)
            + wh[2] * fmaxf(d[2][s], 0.f) + wh[3] * fmaxf(d[3][s], 0.f);
    sc[s] = (n * 16 + 15 < t) ? v : -INFINITY;
  }
  float bv = -INFINITY; int bs = 0;
  #pragma unroll
  for (int s = 0; s < 8; ++s) if (sc[s] > bv) { bv = sc[s]; bs = s; }

  int* orow = top_idx + (size_t)t * 64;
  for (int j = 0; j < 64; ++j) {
    float v = bv; int n = lane * 8 + bs;
    #pragma unroll
    for (int off = 32; off >= 1; off >>= 1) {
      float ov = __shfl_xor(v, off);
      int   on = __shfl_xor(n, off);
      if (ov > v || (ov == v && on < n)) { v = ov; n = on; }
    }
    if (lane == 0) orow[j] = (v > -INFINITY) ? n : -1;
    if (v > -INFINITY && (n >> 3) == lane) {
      int rs = n & 7;
      #pragma unroll
      for (int s = 0; s < 8; ++s) sc[s] = (s == rs) ? -INFINITY : sc[s];
      bv = -INFINITY; bs = 0;
      #pragma unroll
      for (int s = 0; s < 8; ++s) if (sc[s] > bv) { bv = sc[s]; bs = s; }
    }
  }
}

// ---------------------------------------------------------------------------
// Sparse attention (q bf16, ckv f32 pre-normalized) -> attn bf16 (writes).
// ---------------------------------------------------------------------------
__global__ __launch_bounds__(256) void sparse_attn_k(
    const u16* __restrict__ q,       // (T, 16, 128) bf16
    const float* __restrict__ nckv,  // (512, 128)
    const int* __restrict__ top_idx, // (T, 64)
    u16* __restrict__ attn)          // (T, 16, 128) bf16
{
  int t = blockIdx.x;
  int tid = threadIdx.x;
  __shared__ float skv[64][132];
  __shared__ float qs[16][132];
  __shared__ float sc[16][65];
  __shared__ int ivals[64];
  if (tid < 64) ivals[tid] = top_idx[(size_t)t * 64 + tid];
  __syncthreads();
  {
    int r = tid >> 2;
    int c0 = (tid & 3) * 32;
    int gi = ivals[r] >= 0 ? ivals[r] : 0;
    #pragma unroll
    for (int i = 0; i < 32; ++i)
      skv[r][c0 + i] = nckv[(size_t)gi * 128 + c0 + i];
  }
  for (int e = tid; e < 2048; e += 256)
    qs[e >> 7][e & 127] = b2f(q[(size_t)t * 2048 + e]);
  __syncthreads();
  for (int e = tid; e < 1024; e += 256) {
    int h = e >> 6, k = e & 63;
    const float4* qa = (const float4*)qs[h];
    const float4* kb = (const float4*)skv[k];
    float d = 0.f;
    #pragma unroll
    for (int i = 0; i < 32; ++i) {
      float4 a = qa[i], b = kb[i];
      d += a.x * b.x + a.y * b.y + a.z * b.z + a.w * b.w;
    }
    sc[h][k] = (ivals[k] >= 0) ? d * SCALE : -INFINITY;
  }
  __syncthreads();
  int h = tid >> 4;
  int d0 = (tid & 15) * 8;
  float m = -INFINITY;
  #pragma unroll
  for (int k = 0; k < 64; ++k) m = fmaxf(m, sc[h][k]);
  float o[8] = {};
  if (m > -INFINITY) {
    float l = 0.f;
    for (int k = 0; k < 64; ++k) {
      float p = expf(sc[h][k] - m);
      l += p;
      #pragma unroll
      for (int i = 0; i < 8; ++i) o[i] += p * skv[k][d0 + i];
    }
    float inv = 1.0f / l;
    #pragma unroll
    for (int i = 0; i < 8; ++i) o[i] *= inv;
  }
  #pragma unroll
  for (int i = 0; i < 8; ++i)
    attn[(size_t)t * 2048 + h * 128 + d0 + i] = f2b(o[i]);
}

// ---------------------------------------------------------------------------
// Sliding-window attention, bf16 MFMA flash.  Block = (64-q tile, head),
// 4 waves x 16 q-rows.  K swizzled in LDS, V transposed+padded, P via
// per-wave LDS.  attn (bf16) +=.
// ---------------------------------------------------------------------------
__global__ __launch_bounds__(256) void win_attn_mfma_k(
    const u16* __restrict__ q,     // (T, 16, 128) bf16
    const float* __restrict__ kv,  // (T, 512) f32: k@0, v@128
    u16* __restrict__ attn)        // (T, 16, 128) bf16 +=
{
  const int qt = blockIdx.x, hh = blockIdx.y;
  const int tid = threadIdx.x;
  const int wid = tid >> 6, lane = tid & 63;
  const int low = lane & 15, grp = lane >> 4;

  __shared__ __align__(16) u16 Ks[64 * 128];
  __shared__ __align__(16) u16 Vt[128 * 72];
  __shared__ __align__(16) u16 Pl[4][16 * 72];

  u16x8 qf[4];
  {
    const u16* qp = q + (size_t)(qt * 64 + wid * 16 + low) * 2048 + hh * 128 + grp * 8;
    #pragma unroll
    for (int kk = 0; kk < 4; ++kk) qf[kk] = *(const u16x8*)(qp + kk * 32);
  }
  f32x4 zero = {0.f, 0.f, 0.f, 0.f};
  f32x4 o[8];
  #pragma unroll
  for (int dt = 0; dt < 8; ++dt) o[dt] = zero;
  float mrow[4] = {-1e30f, -1e30f, -1e30f, -1e30f};
  float lrow[4] = {0.f, 0.f, 0.f, 0.f};

  const int kt0 = qt >= 4 ? qt - 4 : 0;
  const int srow = tid >> 2;
  const int scol = (tid & 3) * 32;
  for (int kt = kt0; kt <= qt; ++kt) {
    __syncthreads();
    {
      const float* gk = kv + (size_t)(kt * 64 + srow) * 512 + scol;
      u16 tmp[32];
      #pragma unroll
      for (int i = 0; i < 32; i += 4) {
        float4 v = *(const float4*)(gk + i);
        tmp[i] = f2b(v.x); tmp[i+1] = f2b(v.y); tmp[i+2] = f2b(v.z); tmp[i+3] = f2b(v.w);
      }
      #pragma unroll
      for (int j = 0; j < 4; ++j) {
        int c = scol + j * 8;
        *(u16x8*)(Ks + srow * 128 + (c ^ ((srow & 7) << 3))) = *(const u16x8*)(tmp + j * 8);
      }
      const float* gv = gk + 128;
      #pragma unroll
      for (int i = 0; i < 32; i += 4) {
        float4 v = *(const float4*)(gv + i);
        Vt[(scol + i + 0) * 72 + srow] = f2b(v.x);
        Vt[(scol + i + 1) * 72 + srow] = f2b(v.y);
        Vt[(scol + i + 2) * 72 + srow] = f2b(v.z);
        Vt[(scol + i + 3) * 72 + srow] = f2b(v.w);
      }
    }
    __syncthreads();
    f32x4 s[4];
    #pragma unroll
    for (int n = 0; n < 4; ++n) {
      s[n] = zero;
      int krow = n * 16 + low;
      #pragma unroll
      for (int kk = 0; kk < 4; ++kk) {
        u16x8 kf = *(const u16x8*)(Ks + krow * 128 + ((kk * 32 + grp * 8) ^ ((krow & 7) << 3)));
        mfma16(s[n], qf[kk], kf);
      }
    }
    asm volatile("s_nop 7\n\ts_nop 7");
    const int qg = qt * 64 + wid * 16 + grp * 4;
    #pragma unroll
    for (int n = 0; n < 4; ++n) {
      int kg = kt * 64 + n * 16 + low;
      #pragma unroll
      for (int r = 0; r < 4; ++r) {
        bool ok = (kg <= qg + r) && (kg > qg + r - 256);
        s[n][r] = ok ? s[n][r] * SCALE : -1e30f;
      }
    }
    float p[4][4];
    #pragma unroll
    for (int r = 0; r < 4; ++r) {
      float rm = fmaxf(fmaxf(s[0][r], s[1][r]), fmaxf(s[2][r], s[3][r]));
      rm = fmaxf(rm, __shfl_xor(rm, 1));
      rm = fmaxf(rm, __shfl_xor(rm, 2));
      rm = fmaxf(rm, __shfl_xor(rm, 4));
      rm = fmaxf(rm, __shfl_xor(rm, 8));
      float nm = fmaxf(mrow[r], rm);
      float f = __expf(mrow[r] - nm);
      mrow[r] = nm;
      float ps = 0.f;
      #pragma unroll
      for (int n = 0; n < 4; ++n) { p[n][r] = __expf(s[n][r] - nm); ps += p[n][r]; }
      ps += __shfl_xor(ps, 1); ps += __shfl_xor(ps, 2);
      ps += __shfl_xor(ps, 4); ps += __shfl_xor(ps, 8);
      lrow[r] = lrow[r] * f + ps;
      #pragma unroll
      for (int dt = 0; dt < 8; ++dt) o[dt][r] *= f;
    }
    u16* pw = Pl[wid];
    #pragma unroll
    for (int n = 0; n < 4; ++n)
      #pragma unroll
      for (int r = 0; r < 4; ++r)
        pw[(grp * 4 + r) * 72 + n * 16 + low] = f2b(p[n][r]);
    #pragma unroll
    for (int kk2 = 0; kk2 < 2; ++kk2) {
      u16x8 pa = *(const u16x8*)(pw + low * 72 + kk2 * 32 + grp * 8);
      #pragma unroll
      for (int dt = 0; dt < 8; ++dt) {
        u16x8 vf = *(const u16x8*)(Vt + (dt * 16 + low) * 72 + kk2 * 32 + grp * 8);
        mfma16(o[dt], pa, vf);
      }
    }
  }
  asm volatile("s_nop 7\n\ts_nop 7");
  float linv[4];
  #pragma unroll
  for (int r = 0; r < 4; ++r) linv[r] = 1.0f / lrow[r];
  u16* ap = attn + (size_t)(qt * 64 + wid * 16 + grp * 4) * 2048 + hh * 128 + low;
  #pragma unroll
  for (int r = 0; r < 4; ++r)
    #pragma unroll
    for (int dt = 0; dt < 8; ++dt) {
      size_t idx = (size_t)r * 2048 + dt * 16;
      ap[idx] = f2b(b2f(ap[idx]) + o[dt][r] * linv[r]);
    }
}

// ---------------------------------------------------------------------------
extern "C" void kernel_launch(void* const* d_in, const int* in_sizes, int n_in,
                              void* d_out, int out_size, void* d_ws, size_t ws_size,
                              hipStream_t stream)
{
  const float* h        = (const float*)d_in[0];
  const float* w_qc     = (const float*)d_in[1];
  const float* w_qup    = (const float*)d_in[2];
  const float* kvc_w    = (const float*)d_in[3];
  const float* kvc_wz   = (const float*)d_in[4];
  const float* kvc_bias = (const float*)d_in[5];
  const float* k_proj_w = (const float*)d_in[6];
  const float* v_proj_w = (const float*)d_in[7];
  const float* idx_c_w  = (const float*)d_in[8];
  const float* idx_c_wz = (const float*)d_in[9];
  const float* idx_c_bias = (const float*)d_in[10];
  const float* w_dq     = (const float*)d_in[11];
  const float* w_iuq    = (const float*)d_in[12];
  const float* w_w      = (const float*)d_in[13];
  const float* q_norm_w = (const float*)d_in[14];
  const float* k_norm_w = (const float*)d_in[15];
  const float* group_w  = (const float*)d_in[16];
  const float* final_w  = (const float*)d_in[17];
  float* out = (float*)d_out;

  float* ws = (float*)d_ws;
  size_t off = 0;
  auto alloc = [&](size_t nfloats) { float* p = ws + off; off += nfloats; return p; };
  float* cosT  = alloc((size_t)T_LEN * 32);
  float* sinT  = alloc((size_t)T_LEN * 32);
  u16* qb      = (u16*)alloc((size_t)T_LEN * 1024);
  u16* attnb   = (u16*)alloc((size_t)T_LEN * 1024);
  u16* hb      = (u16*)alloc((size_t)T_LEN * 1024);
  float* kvout = alloc((size_t)T_LEN * 512);
  float* ibuf  = alloc((size_t)T_LEN * 228);
  float* kT    = alloc((size_t)64 * NBLK);
  float* ckv   = alloc((size_t)NBLK * 128);
  float* qib   = alloc((size_t)T_LEN * 256);
  int*   topi  = (int*)alloc((size_t)T_LEN * 64);
  u16* w_qcT   = (u16*)alloc((size_t)512 * 1024);     // rows 0-511 of fused B
  u16* kvT     = (u16*)alloc((size_t)512 * 1024);     // rows 512-1023 (contiguous!)
  u16* w_qupT  = (u16*)alloc((size_t)2048 * 256);
  u16* gwT     = (u16*)alloc((size_t)4 * 512 * 256);
  u16* fwT     = (u16*)alloc((size_t)2048 * 1024);
  float* part  = alloc((size_t)4 * T_LEN * NIDX);     // split-K partials
  float* Bcat  = (float*)attnb;                       // 2048 x 196 f32
  u16* hq1b    = (u16*)((float*)attnb + 524288);
  u16* og      = qb;

  rope_cs_k<<<(T_LEN * 32 + 255) / 256, 256, 0, stream>>>(cosT, sinT);
  castk<<<(T_LEN * 2048 / 4 + 255) / 256, 256, 0, stream>>>(h, hb, T_LEN * 2048 / 4);
  tcast_k<<<dim3(16, 64), 256, 0, stream>>>(w_qc, w_qcT, 2048, 512);
  tcast_k<<<dim3(4, 64), 256, 0, stream>>>(k_proj_w, kvT + (size_t)0 * 128 * 2048, 2048, 128);
  tcast_k<<<dim3(4, 64), 256, 0, stream>>>(v_proj_w, kvT + (size_t)1 * 128 * 2048, 2048, 128);
  tcast_k<<<dim3(4, 64), 256, 0, stream>>>(kvc_w,    kvT + (size_t)2 * 128 * 2048, 2048, 128);
  tcast_k<<<dim3(4, 64), 256, 0, stream>>>(kvc_wz,   kvT + (size_t)3 * 128 * 2048, 2048, 128);
  tcast_k<<<dim3(64, 16), 256, 0, stream>>>(w_qup, w_qupT, 512, 2048);
  for (int g = 0; g < 4; ++g)
    tcast_k<<<dim3(16, 16), 256, 0, stream>>>(group_w + (size_t)g * 512 * 512,
                                              gwT + (size_t)g * 512 * 512, 512, 512);
  tcast_k<<<dim3(64, 64), 256, 0, stream>>>(final_w, fwT, 2048, 2048);
  concat_idx_k<<<(2048 * NIDX + 255) / 256, 256, 0, stream>>>(idx_c_w, idx_c_wz, w_dq, w_w, Bcat);

  // fused qc + k|v|kvc projections (one N=1024 bf16 MFMA GEMM, split outputs)
  bgemm_qckv_k<<<dim3(8, 64), 256, 0, stream>>>(hb, w_qcT, hq1b, kvout);

  // q chain tail
  bgemm_k<1><<<dim3(16, 64), 256, 0, stream>>>(hq1b, 512, w_qupT, 512, qb, 2048, 512);
  q_rope_norm_k<<<T_LEN * 4, 256, 0, stream>>>(qb, cosT, sinT, q_norm_w);

  // sliding-window k norm/rope + kv compression
  k_norm_rope_k<<<T_LEN / 4, 256, 0, stream>>>(kvout, cosT, sinT, k_norm_w);
  compress_k<<<(NBLK * 128 + 255) / 256, 256, 0, stream>>>(
      kvout + 256, kvout + 384, 512, kvc_bias, ckv, 128, 128, 1);
  rms_rows_k<<<NBLK / 4, 256, 0, stream>>>(ckv, k_norm_w);

  // index path (f32 exact for selection stability; split-K for occupancy)
  sgemm_splitk_k<<<dim3(4, 128, 4), 256, 0, stream>>>(h, HID, Bcat, NIDX, part, NIDX, T_LEN, NIDX, 512);
  reduce4_k<<<(T_LEN * NIDX + 255) / 256, 256, 0, stream>>>(part, NIDX, ibuf, 228, T_LEN);
  compress_k<<<(NBLK * 64 + 255) / 256, 256, 0, stream>>>(
      ibuf, ibuf + 64, 228, idx_c_bias, kT, 64, 1, NBLK);
  sgemm_k<<<dim3(4, 128), 256, 0, stream>>>(ibuf + 128, 228, w_iuq, 256, qib, 256, T_LEN, 256, 64);
  topk_k<<<T_LEN / 4, 256, 0, stream>>>(qib, ibuf + 192, 228, kT, topi);

  // attention
  sparse_attn_k<<<T_LEN, 256, 0, stream>>>(qb, ckv, topi, attnb);
  win_attn_mfma_k<<<dim3(T_LEN / 64, 16), 256, 0, stream>>>(qb, kvout, attnb);

  // output projections (bf16 MFMA): fused group projection, then final
  bgemm_group_k<<<dim3(4, 64, 4), 256, 0, stream>>>(attnb, gwT, og);
  bgemm_k<0><<<dim3(16, 64), 256, 0, stream>>>(og, 2048, fwT, 2048, out, 2048, 2048);
}